// Round 3
// baseline (444.357 us; speedup 1.0000x reference)
//
#include <hip/hip_runtime.h>
#include <hip/hip_bf16.h>

#define NB   32
#define C    256
#define CI   128
#define HW   4096
#define NHW  131072

typedef __attribute__((ext_vector_type(8))) short short8;
typedef __attribute__((ext_vector_type(4))) float floatx4;

__device__ __forceinline__ unsigned short f2bf(float f) {
    unsigned int u = __float_as_uint(f);
    return (unsigned short)((u + 0x7fffu + ((u >> 16) & 1u)) >> 16);
}
__device__ __forceinline__ unsigned short f2h(float f) {
    _Float16 h = (_Float16)f;
    return __builtin_bit_cast(unsigned short, h);
}
__device__ __forceinline__ float h2f(unsigned short u) {
    _Float16 h = __builtin_bit_cast(_Float16, u);
    return (float)h;
}

// async global->LDS, 16B per lane, wave-uniform LDS base + lane*16
__device__ __forceinline__ void gl16(const void* g, void* l) {
    __builtin_amdgcn_global_load_lds(
        (const __attribute__((address_space(1))) unsigned int*)g,
        (__attribute__((address_space(3))) unsigned int*)l, 16, 0, 0);
}

// ---------------------------------------------------------------------------
// K0: fused cast+transpose (x fp32 [n][c][t] -> xT bf16 [n][t][c]) + channel sums.
// grid (64 t-tiles, 4 c-tiles, 32 n), block 256.
__global__ __launch_bounds__(256) void k_prep(const float* __restrict__ x,
        unsigned short* __restrict__ xT, float* __restrict__ s) {
    const int n = blockIdx.z, c0 = blockIdx.y * 64, t0 = blockIdx.x * 64;
    __shared__ float sA[64][68];
    const int tid = threadIdx.x;
    const int cr = tid >> 4;          // 0..15
    const int tq = (tid & 15) * 4;    // 0..60
#pragma unroll
    for (int pass = 0; pass < 4; ++pass) {
        const int c = cr + pass * 16;
        const float4 v = *(const float4*)&x[((size_t)n * C + c0 + c) * HW + t0 + tq];
        const int swz = ((c >> 3) & 7) * 8;
        *(float4*)&sA[c][tq ^ swz] = v;
        float ps = v.x + v.y + v.z + v.w;
        for (int off = 1; off < 16; off <<= 1) ps += __shfl_xor(ps, off, 64);
        if ((tid & 15) == 0) atomicAdd(&s[n * C + c0 + c], ps);
    }
    __syncthreads();
    // write xT rows: 32 t-rows per pass, 8 threads/row, 8 c each
    const int tr = tid >> 3;          // 0..31
    const int cc = (tid & 7) * 8;     // 0..56
#pragma unroll
    for (int pass = 0; pass < 2; ++pass) {
        const int t = tr + pass * 32;
        unsigned int w[4];
#pragma unroll
        for (int jj = 0; jj < 4; ++jj) {
            const int ca = cc + 2 * jj, cb = cc + 2 * jj + 1;
            unsigned short lo = f2bf(sA[ca][t ^ (((ca >> 3) & 7) * 8)]);
            unsigned short hi = f2bf(sA[cb][t ^ (((cb >> 3) & 7) * 8)]);
            w[jj] = (unsigned int)lo | ((unsigned int)hi << 16);
        }
        uint4 u4; u4.x = w[0]; u4.y = w[1]; u4.z = w[2]; u4.w = w[3];
        *(uint4*)&xT[((size_t)n * HW + t0 + t) * C + c0 + cc] = u4;
    }
}

// ---------------------------------------------------------------------------
// K1+K2 fused: theta/phi (kept in LDS) + softmax rows of A + q. grid 32, block 128.
__global__ __launch_bounds__(128) void k_attn(const float* __restrict__ s,
        const float* __restrict__ w_theta, const float* __restrict__ b_theta,
        const float* __restrict__ w_phi,  const float* __restrict__ b_phi,
        const float* __restrict__ b_g,
        float* __restrict__ A, float* __restrict__ q) {
    const int n = blockIdx.x, d = threadIdx.x;
    __shared__ float sh_s[C];
    __shared__ float sh_th[CI], sh_ph[CI], sh_pm[2];
    __shared__ float smax[2], smin[2];
    sh_s[d]       = s[n * C + d];
    sh_s[d + 128] = s[n * C + d + 128];
    __syncthreads();
    float td = 0.f, pd = 0.f;
    for (int c = 0; c < C; ++c) {
        const float sv = sh_s[c] * (1.f / 16.f);
        td += w_theta[d * C + c] * sv;
        pd += w_phi[d * C + c] * sv;
    }
    td = (td + 256.f * b_theta[d]) * 0.08838834764831845f;
    pd = pd + 256.f * b_phi[d];
    sh_th[d] = td;
    sh_ph[d] = pd;
    float pmax = pd, pmin = pd;
    for (int off = 32; off; off >>= 1) {
        pmax = fmaxf(pmax, __shfl_xor(pmax, off, 64));
        pmin = fminf(pmin, __shfl_xor(pmin, off, 64));
    }
    if ((d & 63) == 0) { smax[d >> 6] = pmax; smin[d >> 6] = pmin; }
    __syncthreads();
    if (d == 0) {
        sh_pm[0] = fmaxf(smax[0], smax[1]);
        sh_pm[1] = fminf(smin[0], smin[1]);
    }
    __syncthreads();
    // phase 2: each wave handles 64 softmax rows, lanes across 128 d (2 each)
    const int wv = d >> 6, lane = d & 63;
    const float2 phv = *(const float2*)&sh_ph[lane * 2];
    const float2 bg  = *(const float2*)&b_g[lane * 2];
    const float pmx = sh_pm[0], pmn = sh_pm[1];
    for (int r = 0; r < 64; ++r) {
        const int c = wv * 64 + r;
        const float thc = sh_th[c];
        const float m = (thc >= 0.f) ? thc * pmx : thc * pmn;
        float e0 = __expf(thc * phv.x - m);
        float e1 = __expf(thc * phv.y - m);
        float z = e0 + e1;
        for (int off = 32; off; off >>= 1) z += __shfl_xor(z, off, 64);
        const float inv = 1.f / z;
        e0 *= inv; e1 *= inv;
        float2 av; av.x = e0; av.y = e1;
        *(float2*)&A[((size_t)n * CI + c) * CI + lane * 2] = av;
        float qv = e0 * bg.x + e1 * bg.y;
        for (int off = 32; off; off >>= 1) qv += __shfl_xor(qv, off, 64);
        if (lane == 0) q[n * CI + c] = qv;
    }
}

// ---------------------------------------------------------------------------
// K3: W_n[o,d] = sum_c w_out[o,c] * A_n[c,d];  cvec[n,o] = w_out[o,:].q_n + b_out[o]
__global__ __launch_bounds__(128) void k_W(const float* __restrict__ w_out,
        const float* __restrict__ A, const float* __restrict__ q,
        const float* __restrict__ b_out,
        float* __restrict__ W, float* __restrict__ cvec) {
    const int n = blockIdx.x >> 8, o = blockIdx.x & 255, d = threadIdx.x;
    float acc = 0.f;
    for (int c = 0; c < CI; ++c)
        acc += w_out[o * CI + c] * A[((size_t)n * CI + c) * CI + d];
    W[((size_t)n * C + o) * CI + d] = acc;
    if (d == 0) {
        float cv = 0.f;
        for (int c = 0; c < CI; ++c) cv += w_out[o * CI + c] * q[n * CI + c];
        cvec[n * C + o] = cv + b_out[o];
    }
}

// ---------------------------------------------------------------------------
// K4: M_n[o,c2] = sum_d W_n[o,d] * w_g[d,c2]  (fp32 + bf16 copies)
// 16 o-rows per block so w_g streams once per block.
__global__ __launch_bounds__(256) void k_M(const float* __restrict__ W,
        const float* __restrict__ w_g, float* __restrict__ M,
        unsigned short* __restrict__ Mb16) {
    const int n = blockIdx.x >> 4, o0 = (blockIdx.x & 15) * 16;
    const int tid = threadIdx.x, c2 = tid;
    __shared__ float sWt[CI][20];
    for (int idx = tid; idx < 16 * CI; idx += 256) {
        const int oo = idx >> 7, d = idx & 127;
        sWt[d][oo] = W[((size_t)n * C + o0 + oo) * CI + d];
    }
    __syncthreads();
    float acc[16] = {};
    for (int d = 0; d < CI; ++d) {
        const float g = w_g[d * C + c2];
        const float4 w0 = *(const float4*)&sWt[d][0];
        const float4 w1 = *(const float4*)&sWt[d][4];
        const float4 w2 = *(const float4*)&sWt[d][8];
        const float4 w3 = *(const float4*)&sWt[d][12];
        acc[0]  += w0.x * g;  acc[1]  += w0.y * g;
        acc[2]  += w0.z * g;  acc[3]  += w0.w * g;
        acc[4]  += w1.x * g;  acc[5]  += w1.y * g;
        acc[6]  += w1.z * g;  acc[7]  += w1.w * g;
        acc[8]  += w2.x * g;  acc[9]  += w2.y * g;
        acc[10] += w2.z * g;  acc[11] += w2.w * g;
        acc[12] += w3.x * g;  acc[13] += w3.y * g;
        acc[14] += w3.z * g;  acc[15] += w3.w * g;
    }
    float* Mp = M + ((size_t)n * C + o0) * C + c2;
#pragma unroll
    for (int oo = 0; oo < 16; ++oo) Mp[(size_t)oo * C] = acc[oo];
    if (Mb16) {
        unsigned short* Mbp = Mb16 + ((size_t)n * C + o0) * C + c2;
#pragma unroll
        for (int oo = 0; oo < 16; ++oo) Mbp[(size_t)oo * C] = f2bf(acc[oo]);
    }
}

// ---------------------------------------------------------------------------
// K5: MFMA GEMM  p[n] = M_n @ x[n] + cvec, **fp16 out to ws p16**.
// LDS-staged, double-buffered (global_load_lds width=16), BK=32, 128x128 tile.
// Epilogue accumulates per-(n,channel) BN partials (sum p, sum p^2) in fp32.
__global__ __launch_bounds__(256, 4) void k_gemm_mfma(
        const unsigned short* __restrict__ xT,   // [n][4096][256] bf16
        const unsigned short* __restrict__ Mb,   // [n][256][256] bf16
        const float* __restrict__ cvec,
        unsigned short* __restrict__ p16,        // [n][256][4096] fp16
        float* __restrict__ bsum, float* __restrict__ bsq) {
    const int n  = blockIdx.y;
    const int tt = (blockIdx.x & 31) * 128;
    const int ot = (blockIdx.x >> 5) * 128;
    const int tid = threadIdx.x;
    const int wave = tid >> 6, lane = tid & 63;
    const int wm = (wave >> 1) * 64, wn = (wave & 1) * 64;
    const int l15 = lane & 15, q4 = lane >> 4;   // logical 16B k-slot 0..3

    __shared__ unsigned short lA[2][128 * 32];   // [row 128][k 32], 8 KB/buf
    __shared__ unsigned short lB[2][128 * 32];

    const int srow  = tid >> 2;                      // 0..63 (+64 for 2nd call)
    const int sslot = (tid & 3) ^ (srow & 3);
    const unsigned short* gA = Mb + ((size_t)n * C + ot + srow) * C + sslot * 8;
    const unsigned short* gB = xT + ((size_t)n * HW + tt + srow) * C + sslot * 8;
    const int wbase = (tid & ~63) * 8;               // wave-uniform LDS ushort idx

#define STAGE(bf, k0) do { \
        gl16(gA + (k0),           &lA[bf][wbase]); \
        gl16(gA + (k0) + 64 * C,  &lA[bf][2048 + wbase]); \
        gl16(gB + (k0),           &lB[bf][wbase]); \
        gl16(gB + (k0) + 64 * C,  &lB[bf][2048 + wbase]); \
    } while (0)

    const int aoff = (wm + l15) * 32 + ((q4 ^ (l15 & 3)) * 8);
    const int boff = (wn + l15) * 32 + ((q4 ^ (l15 & 3)) * 8);

    floatx4 acc[4][4] = {};
    STAGE(0, 0);
    for (int kt = 0; kt < 8; ++kt) {
        __syncthreads();                 // drains vmcnt: buf[kt&1] staged & safe
        const int b = kt & 1;
        if (kt < 7) STAGE(b ^ 1, (kt + 1) * 32);   // async prefetch next tile
        short8 a[4], bb[4];
#pragma unroll
        for (int i = 0; i < 4; ++i) a[i]  = *(const short8*)&lA[b][aoff + i * 512];
#pragma unroll
        for (int j = 0; j < 4; ++j) bb[j] = *(const short8*)&lB[b][boff + j * 512];
#pragma unroll
        for (int i = 0; i < 4; ++i)
#pragma unroll
            for (int j = 0; j < 4; ++j)
                acc[i][j] = __builtin_amdgcn_mfma_f32_16x16x32_bf16(
                    a[i], bb[j], acc[i][j], 0, 0, 0);
    }
#undef STAGE

    const int quad = lane >> 4;
#pragma unroll
    for (int i = 0; i < 4; ++i) {
        const int rowb = ot + wm + i * 16 + quad * 4;
#pragma unroll
        for (int r = 0; r < 4; ++r) {
            const int row = rowb + r;
            const float cv = cvec[n * C + row];
            unsigned short* orow = p16 + ((size_t)n * C + row) * HW + tt + wn + l15;
            const float v0 = acc[i][0][r] + cv;
            const float v1 = acc[i][1][r] + cv;
            const float v2 = acc[i][2][r] + cv;
            const float v3 = acc[i][3][r] + cv;
            orow[0]  = f2h(v0);
            orow[16] = f2h(v1);
            orow[32] = f2h(v2);
            orow[48] = f2h(v3);
            float s0 = v0 + v1 + v2 + v3;
            float s1 = v0 * v0 + v1 * v1 + v2 * v2 + v3 * v3;
#pragma unroll
            for (int off = 1; off < 16; off <<= 1) {
                s0 += __shfl_xor(s0, off, 64);
                s1 += __shfl_xor(s1, off, 64);
            }
            if (l15 == 0) {
                atomicAdd(&bsum[n * C + row], s0);
                atomicAdd(&bsq [n * C + row], s1);
            }
        }
    }
}

// ---------------------------------------------------------------------------
// K5-fallback: fp32 SGEMM (no atomics) if ws too small for xT.
#define BM 64
#define BN 64
#define BK 16
__global__ __launch_bounds__(256) void k_gemm_f32(const float* __restrict__ x,
        const float* __restrict__ M, const float* __restrict__ cvec,
        float* __restrict__ pout) {
    const int n  = blockIdx.y;
    const int ot = (blockIdx.x >> 6) * BM;
    const int tt = (blockIdx.x & 63) * BN;
    const float* Mb = M + (size_t)n * C * C;
    const float* xb = x + (size_t)n * C * HW;
    __shared__ float sA[BK][BM];
    __shared__ float sB[BK][BN];
    const int tid = threadIdx.x;
    const int ty = tid >> 4, tx = tid & 15;
    float acc[4][4] = {};
    for (int k0 = 0; k0 < C; k0 += BK) {
        {
            int row = tid >> 2, kq = (tid & 3) << 2;
            const float4 v = *(const float4*)&Mb[(size_t)(ot + row) * C + k0 + kq];
            sA[kq + 0][row] = v.x; sA[kq + 1][row] = v.y;
            sA[kq + 2][row] = v.z; sA[kq + 3][row] = v.w;
        }
        {
            int krow = tid >> 4, tq2 = (tid & 15) << 2;
            const float4 v = *(const float4*)&xb[(size_t)(k0 + krow) * HW + tt + tq2];
            *(float4*)&sB[krow][tq2] = v;
        }
        __syncthreads();
#pragma unroll
        for (int kk = 0; kk < BK; ++kk) {
            float a[4], b[4];
#pragma unroll
            for (int i = 0; i < 4; ++i) a[i] = sA[kk][ty * 4 + i];
#pragma unroll
            for (int j = 0; j < 4; ++j) b[j] = sB[kk][tx * 4 + j];
#pragma unroll
            for (int i = 0; i < 4; ++i)
#pragma unroll
                for (int j = 0; j < 4; ++j) acc[i][j] += a[i] * b[j];
        }
        __syncthreads();
    }
#pragma unroll
    for (int i = 0; i < 4; ++i) {
        const int o = ot + ty * 4 + i;
        const float cv = cvec[n * C + o];
        float4 v;
        v.x = acc[i][0] + cv; v.y = acc[i][1] + cv;
        v.z = acc[i][2] + cv; v.w = acc[i][3] + cv;
        *(float4*)&pout[((size_t)n * C + o) * HW + tt + tx * 4] = v;
    }
}

// ---------------------------------------------------------------------------
// K6 (fallback path only): per-channel BN stats -> scale/shift.
__global__ __launch_bounds__(256) void k_bnstat(const float* __restrict__ p,
        const float* __restrict__ gamma, const float* __restrict__ beta,
        float* __restrict__ scale, float* __restrict__ shift) {
    const int o = blockIdx.x;
    float s0 = 0.f, s1 = 0.f;
    for (int n = 0; n < NB; ++n) {
        const float4* pp = (const float4*)(p + ((size_t)n * C + o) * HW);
        for (int i = threadIdx.x; i < HW / 4; i += 256) {
            const float4 v = pp[i];
            s0 += v.x + v.y + v.z + v.w;
            s1 += v.x * v.x + v.y * v.y + v.z * v.z + v.w * v.w;
        }
    }
    for (int off = 32; off; off >>= 1) {
        s0 += __shfl_down(s0, off, 64);
        s1 += __shfl_down(s1, off, 64);
    }
    __shared__ float r0[4], r1[4];
    if ((threadIdx.x & 63) == 0) { r0[threadIdx.x >> 6] = s0; r1[threadIdx.x >> 6] = s1; }
    __syncthreads();
    if (threadIdx.x == 0) {
        const float S0 = r0[0] + r0[1] + r0[2] + r0[3];
        const float S1 = r1[0] + r1[1] + r1[2] + r1[3];
        const float mean = S0 * (1.f / (float)NHW);
        const float var  = S1 * (1.f / (float)NHW) - mean * mean;
        const float sc   = gamma[o] * rsqrtf(var + 1e-5f);
        scale[o] = sc;
        shift[o] = beta[o] - mean * sc;
    }
}

// ---------------------------------------------------------------------------
// K6': reduce per-(n,o) GEMM partials -> scale/shift. 1 block, 256 threads.
__global__ __launch_bounds__(256) void k_scale(const float* __restrict__ bsum,
        const float* __restrict__ bsq,
        const float* __restrict__ gamma, const float* __restrict__ beta,
        float* __restrict__ scale, float* __restrict__ shift) {
    const int o = threadIdx.x;
    float S0 = 0.f, S1 = 0.f;
    for (int n = 0; n < NB; ++n) {
        S0 += bsum[n * C + o];
        S1 += bsq [n * C + o];
    }
    const float mean = S0 * (1.f / (float)NHW);
    const float var  = S1 * (1.f / (float)NHW) - mean * mean;
    const float sc   = gamma[o] * rsqrtf(var + 1e-5f);
    scale[o] = sc;
    shift[o] = beta[o] - mean * sc;
}

// ---------------------------------------------------------------------------
// K7: out = x + scale[c]*p16 + shift[c]   (p16 fp16 in ws, out written fresh)
__global__ __launch_bounds__(256) void k_final16(const float* __restrict__ x,
        const unsigned short* __restrict__ p16, float* __restrict__ out,
        const float* __restrict__ scale, const float* __restrict__ shift) {
    const size_t total8 = (size_t)NB * C * HW / 8;
    size_t i = (size_t)blockIdx.x * 256 + threadIdx.x;
    const size_t stride = (size_t)gridDim.x * 256;
    for (; i < total8; i += stride) {
        const int c = (int)((i >> 9) & 255);
        const float sc = scale[c], sh = shift[c];
        const short8 pv = ((const short8*)p16)[i];
        const float4 x0 = ((const float4*)x)[2 * i];
        const float4 x1 = ((const float4*)x)[2 * i + 1];
        float4 r0, r1;
        r0.x = x0.x + sc * h2f((unsigned short)pv[0]) + sh;
        r0.y = x0.y + sc * h2f((unsigned short)pv[1]) + sh;
        r0.z = x0.z + sc * h2f((unsigned short)pv[2]) + sh;
        r0.w = x0.w + sc * h2f((unsigned short)pv[3]) + sh;
        r1.x = x1.x + sc * h2f((unsigned short)pv[4]) + sh;
        r1.y = x1.y + sc * h2f((unsigned short)pv[5]) + sh;
        r1.z = x1.z + sc * h2f((unsigned short)pv[6]) + sh;
        r1.w = x1.w + sc * h2f((unsigned short)pv[7]) + sh;
        ((float4*)out)[2 * i]     = r0;
        ((float4*)out)[2 * i + 1] = r1;
    }
}

// K7-fallback: out = x + scale[c]*p + shift[c]  (in-place on d_out holding fp32 p)
__global__ __launch_bounds__(256) void k_final32(const float* __restrict__ x,
        float* __restrict__ out, const float* __restrict__ scale,
        const float* __restrict__ shift) {
    const size_t total4 = (size_t)NB * C * HW / 4;
    size_t i = (size_t)blockIdx.x * 256 + threadIdx.x;
    const size_t stride = (size_t)gridDim.x * 256;
    for (; i < total4; i += stride) {
        const int c = (int)((i >> 10) & 255);
        const float sc = scale[c], sh = shift[c];
        const float4 xv = ((const float4*)x)[i];
        const float4 pv = ((float4*)out)[i];
        float4 r;
        r.x = xv.x + sc * pv.x + sh;
        r.y = xv.y + sc * pv.y + sh;
        r.z = xv.z + sc * pv.z + sh;
        r.w = xv.w + sc * pv.w + sh;
        ((float4*)out)[i] = r;
    }
}

// fallback channel-sum kernel (only used when ws is too small for xT)
__global__ __launch_bounds__(256) void k_colsum(const float* __restrict__ x,
                                                float* __restrict__ s) {
    const int bc = blockIdx.x;
    const float4* p4 = (const float4*)(x + (size_t)bc * HW);
    const int tid = threadIdx.x;
    float acc = 0.f;
    for (int i = tid; i < HW / 4; i += 256) {
        const float4 v = p4[i];
        acc += v.x + v.y + v.z + v.w;
    }
    for (int off = 32; off; off >>= 1) acc += __shfl_down(acc, off, 64);
    __shared__ float red[4];
    if ((tid & 63) == 0) red[tid >> 6] = acc;
    __syncthreads();
    if (tid == 0) atomicAdd(&s[bc], red[0] + red[1] + red[2] + red[3]);
}

// ---------------------------------------------------------------------------
extern "C" void kernel_launch(void* const* d_in, const int* in_sizes, int n_in,
                              void* d_out, int out_size, void* d_ws, size_t ws_size,
                              hipStream_t stream) {
    const float* x       = (const float*)d_in[0];
    const float* w_theta = (const float*)d_in[1];
    const float* b_theta = (const float*)d_in[2];
    const float* w_phi   = (const float*)d_in[3];
    const float* b_phi   = (const float*)d_in[4];
    const float* w_g     = (const float*)d_in[5];
    const float* b_g     = (const float*)d_in[6];
    const float* w_out   = (const float*)d_in[7];
    const float* b_out   = (const float*)d_in[8];
    const float* gamma   = (const float*)d_in[9];
    const float* beta    = (const float*)d_in[10];
    float* out = (float*)d_out;
    float* ws  = (float*)d_ws;

    // workspace layout (float offsets)
    float* s     = ws;                       // 8192
    float* bsum  = s + NB * C;               // 8192  (BN Σp partials per n,o)
    float* bsq   = bsum + NB * C;            // 8192  (BN Σp² partials per n,o)
    float* A     = bsq + NB * C;             // 524288
    float* q     = A + (size_t)NB * CI * CI; // 4096
    float* W     = q + NB * CI;              // 1048576
    float* M     = W + (size_t)NB * C * CI;  // 2097152
    float* cvec  = M + (size_t)NB * C * C;   // 8192
    float* scale = cvec + NB * C;            // 256
    float* shift = scale + C;                // 256
    unsigned short* Mb16 = (unsigned short*)(shift + C);          // 2097152 u16
    unsigned short* xT   = Mb16 + (size_t)NB * C * C;             // 33554432 u16
    unsigned short* p16  = xT + (size_t)NB * HW * C;              // 33554432 u16
    const size_t need_bytes =
        ((char*)(p16 + (size_t)NB * C * HW) - (char*)ws);
    const bool use_mfma = (ws_size >= need_bytes);

    hipMemsetAsync(s, 0, 3 * NB * C * sizeof(float), stream);  // s + bsum + bsq
    if (use_mfma) {
        k_prep<<<dim3(64, 4, NB), 256, 0, stream>>>(x, xT, s);
    } else {
        k_colsum<<<NB * C, 256, 0, stream>>>(x, s);
    }
    k_attn<<<NB, CI, 0, stream>>>(s, w_theta, b_theta, w_phi, b_phi, b_g, A, q);
    k_W<<<NB * C, CI, 0, stream>>>(w_out, A, q, b_out, W, cvec);
    k_M<<<NB * 16, 256, 0, stream>>>(W, w_g, M, use_mfma ? Mb16 : (unsigned short*)nullptr);
    if (use_mfma) {
        k_gemm_mfma<<<dim3(64, NB), 256, 0, stream>>>(xT, Mb16, cvec, p16, bsum, bsq);
        k_scale<<<1, 256, 0, stream>>>(bsum, bsq, gamma, beta, scale, shift);
        k_final16<<<16384, 256, 0, stream>>>(x, p16, out, scale, shift);
    } else {
        k_gemm_f32<<<dim3(256, NB), 256, 0, stream>>>(x, M, cvec, out);
        k_bnstat<<<C, 256, 0, stream>>>(out, gamma, beta, scale, shift);
        k_final32<<<32768, 256, 0, stream>>>(x, out, scale, shift);
    }
}

// Round 4
// 415.393 us; speedup vs baseline: 1.0697x; 1.0697x over previous
//
#include <hip/hip_runtime.h>
#include <hip/hip_bf16.h>

#define NB   32
#define C    256
#define CI   128
#define HW   4096
#define NHW  131072

typedef __attribute__((ext_vector_type(8))) short short8;
typedef __attribute__((ext_vector_type(4))) float floatx4;

__device__ __forceinline__ unsigned short f2bf(float f) {
    unsigned int u = __float_as_uint(f);
    return (unsigned short)((u + 0x7fffu + ((u >> 16) & 1u)) >> 16);
}
__device__ __forceinline__ unsigned short f2h(float f) {
    _Float16 h = (_Float16)f;
    return __builtin_bit_cast(unsigned short, h);
}
__device__ __forceinline__ float h2f(unsigned short u) {
    _Float16 h = __builtin_bit_cast(_Float16, u);
    return (float)h;
}

// async global->LDS, 16B per lane, wave-uniform LDS base + lane*16
__device__ __forceinline__ void gl16(const void* g, void* l) {
    __builtin_amdgcn_global_load_lds(
        (const __attribute__((address_space(1))) unsigned int*)g,
        (__attribute__((address_space(3))) unsigned int*)l, 16, 0, 0);
}

// ---------------------------------------------------------------------------
// K0: fused cast+transpose (x fp32 [n][c][t] -> xT bf16 [n][t][c]) + channel sums.
// grid (64 t-tiles, 4 c-tiles, 32 n), block 256.
__global__ __launch_bounds__(256) void k_prep(const float* __restrict__ x,
        unsigned short* __restrict__ xT, float* __restrict__ s) {
    const int n = blockIdx.z, c0 = blockIdx.y * 64, t0 = blockIdx.x * 64;
    __shared__ float sA[64][68];
    const int tid = threadIdx.x;
    const int cr = tid >> 4;          // 0..15
    const int tq = (tid & 15) * 4;    // 0..60
#pragma unroll
    for (int pass = 0; pass < 4; ++pass) {
        const int c = cr + pass * 16;
        const float4 v = *(const float4*)&x[((size_t)n * C + c0 + c) * HW + t0 + tq];
        const int swz = ((c >> 3) & 7) * 8;
        *(float4*)&sA[c][tq ^ swz] = v;
        float ps = v.x + v.y + v.z + v.w;
        for (int off = 1; off < 16; off <<= 1) ps += __shfl_xor(ps, off, 64);
        if ((tid & 15) == 0) atomicAdd(&s[n * C + c0 + c], ps);
    }
    __syncthreads();
    // write xT rows: 32 t-rows per pass, 8 threads/row, 8 c each
    const int tr = tid >> 3;          // 0..31
    const int cc = (tid & 7) * 8;     // 0..56
#pragma unroll
    for (int pass = 0; pass < 2; ++pass) {
        const int t = tr + pass * 32;
        unsigned int w[4];
#pragma unroll
        for (int jj = 0; jj < 4; ++jj) {
            const int ca = cc + 2 * jj, cb = cc + 2 * jj + 1;
            unsigned short lo = f2bf(sA[ca][t ^ (((ca >> 3) & 7) * 8)]);
            unsigned short hi = f2bf(sA[cb][t ^ (((cb >> 3) & 7) * 8)]);
            w[jj] = (unsigned int)lo | ((unsigned int)hi << 16);
        }
        uint4 u4; u4.x = w[0]; u4.y = w[1]; u4.z = w[2]; u4.w = w[3];
        *(uint4*)&xT[((size_t)n * HW + t0 + t) * C + c0 + cc] = u4;
    }
}

// ---------------------------------------------------------------------------
// K1: theta/phi vectors per batch + ph max/min. grid 32, block 128.
__global__ __launch_bounds__(128) void k_thph(const float* __restrict__ s,
        const float* __restrict__ w_theta, const float* __restrict__ b_theta,
        const float* __restrict__ w_phi,  const float* __restrict__ b_phi,
        float* __restrict__ th, float* __restrict__ ph, float* __restrict__ pm) {
    const int n = blockIdx.x, d = threadIdx.x;
    __shared__ float sh_s[C];
    __shared__ float smax[2], smin[2];
    sh_s[d]       = s[n * C + d];
    sh_s[d + 128] = s[n * C + d + 128];
    __syncthreads();
    float td = 0.f, pd = 0.f;
    for (int c = 0; c < C; ++c) {
        const float sv = sh_s[c] * (1.f / 16.f);
        td += w_theta[d * C + c] * sv;
        pd += w_phi[d * C + c] * sv;
    }
    td = (td + 256.f * b_theta[d]) * 0.08838834764831845f;
    pd = pd + 256.f * b_phi[d];
    th[n * CI + d] = td;
    ph[n * CI + d] = pd;
    float pmax = pd, pmin = pd;
    for (int off = 32; off; off >>= 1) {
        pmax = fmaxf(pmax, __shfl_xor(pmax, off, 64));
        pmin = fminf(pmin, __shfl_xor(pmin, off, 64));
    }
    if ((d & 63) == 0) { smax[d >> 6] = pmax; smin[d >> 6] = pmin; }
    __syncthreads();
    if (d == 0) {
        pm[n * 2 + 0] = fmaxf(smax[0], smax[1]);
        pm[n * 2 + 1] = fminf(smin[0], smin[1]);
    }
}

// ---------------------------------------------------------------------------
// K2: one softmax row of A per one-wave block. grid NB*CI, block 64.
__global__ __launch_bounds__(64) void k_arow(const float* __restrict__ th,
        const float* __restrict__ ph, const float* __restrict__ pm,
        const float* __restrict__ b_g,
        float* __restrict__ A, float* __restrict__ q) {
    const int n = blockIdx.x >> 7, c = blockIdx.x & 127, lane = threadIdx.x;
    const float thc = th[n * CI + c];
    const float2 phv = *(const float2*)&ph[n * CI + lane * 2];
    const float m = (thc >= 0.f) ? thc * pm[n * 2] : thc * pm[n * 2 + 1];
    float e0 = __expf(thc * phv.x - m);
    float e1 = __expf(thc * phv.y - m);
    float z = e0 + e1;
    for (int off = 32; off; off >>= 1) z += __shfl_xor(z, off, 64);
    const float inv = 1.f / z;
    e0 *= inv; e1 *= inv;
    float2 av; av.x = e0; av.y = e1;
    *(float2*)&A[((size_t)n * CI + c) * CI + lane * 2] = av;
    const float2 bg = *(const float2*)&b_g[lane * 2];
    float qv = e0 * bg.x + e1 * bg.y;
    for (int off = 32; off; off >>= 1) qv += __shfl_xor(qv, off, 64);
    if (lane == 0) q[n * CI + c] = qv;
}

// ---------------------------------------------------------------------------
// K3: W_n[o,d] = sum_c w_out[o,c] * A_n[c,d];  cvec[n,o] = w_out[o,:].q_n + b_out[o]
__global__ __launch_bounds__(128) void k_W(const float* __restrict__ w_out,
        const float* __restrict__ A, const float* __restrict__ q,
        const float* __restrict__ b_out,
        float* __restrict__ W, float* __restrict__ cvec) {
    const int n = blockIdx.x >> 8, o = blockIdx.x & 255, d = threadIdx.x;
    float acc = 0.f;
    for (int c = 0; c < CI; ++c)
        acc += w_out[o * CI + c] * A[((size_t)n * CI + c) * CI + d];
    W[((size_t)n * C + o) * CI + d] = acc;
    if (d == 0) {
        float cv = 0.f;
        for (int c = 0; c < CI; ++c) cv += w_out[o * CI + c] * q[n * CI + c];
        cvec[n * C + o] = cv + b_out[o];
    }
}

// ---------------------------------------------------------------------------
// K4: M_n[o,c2] = sum_d W_n[o,d] * w_g[d,c2]  (fp32 + bf16 copies)
// 16 o-rows per block so w_g streams once per block.
__global__ __launch_bounds__(256) void k_M(const float* __restrict__ W,
        const float* __restrict__ w_g, float* __restrict__ M,
        unsigned short* __restrict__ Mb16) {
    const int n = blockIdx.x >> 4, o0 = (blockIdx.x & 15) * 16;
    const int tid = threadIdx.x, c2 = tid;
    __shared__ float sWt[CI][20];
    for (int idx = tid; idx < 16 * CI; idx += 256) {
        const int oo = idx >> 7, d = idx & 127;
        sWt[d][oo] = W[((size_t)n * C + o0 + oo) * CI + d];
    }
    __syncthreads();
    float acc[16] = {};
    for (int d = 0; d < CI; ++d) {
        const float g = w_g[d * C + c2];
        const float4 w0 = *(const float4*)&sWt[d][0];
        const float4 w1 = *(const float4*)&sWt[d][4];
        const float4 w2 = *(const float4*)&sWt[d][8];
        const float4 w3 = *(const float4*)&sWt[d][12];
        acc[0]  += w0.x * g;  acc[1]  += w0.y * g;
        acc[2]  += w0.z * g;  acc[3]  += w0.w * g;
        acc[4]  += w1.x * g;  acc[5]  += w1.y * g;
        acc[6]  += w1.z * g;  acc[7]  += w1.w * g;
        acc[8]  += w2.x * g;  acc[9]  += w2.y * g;
        acc[10] += w2.z * g;  acc[11] += w2.w * g;
        acc[12] += w3.x * g;  acc[13] += w3.y * g;
        acc[14] += w3.z * g;  acc[15] += w3.w * g;
    }
    float* Mp = M + ((size_t)n * C + o0) * C + c2;
#pragma unroll
    for (int oo = 0; oo < 16; ++oo) Mp[(size_t)oo * C] = acc[oo];
    if (Mb16) {
        unsigned short* Mbp = Mb16 + ((size_t)n * C + o0) * C + c2;
#pragma unroll
        for (int oo = 0; oo < 16; ++oo) Mbp[(size_t)oo * C] = f2bf(acc[oo]);
    }
}

// ---------------------------------------------------------------------------
// K5: MFMA GEMM  p[n] = M_n @ x[n] + cvec, fp16 out to ws p16.
// LDS-staged, double-buffered (global_load_lds width=16), BK=32, 128x128 tile.
// Epilogue accumulates per-(n,channel) BN partials (sum p, sum p^2) in fp32.
__global__ __launch_bounds__(256, 4) void k_gemm_mfma(
        const unsigned short* __restrict__ xT,   // [n][4096][256] bf16
        const unsigned short* __restrict__ Mb,   // [n][256][256] bf16
        const float* __restrict__ cvec,
        unsigned short* __restrict__ p16,        // [n][256][4096] fp16
        float* __restrict__ bsum, float* __restrict__ bsq) {
    const int n  = blockIdx.y;
    const int tt = (blockIdx.x & 31) * 128;
    const int ot = (blockIdx.x >> 5) * 128;
    const int tid = threadIdx.x;
    const int wave = tid >> 6, lane = tid & 63;
    const int wm = (wave >> 1) * 64, wn = (wave & 1) * 64;
    const int l15 = lane & 15, q4 = lane >> 4;   // logical 16B k-slot 0..3

    __shared__ unsigned short lA[2][128 * 32];   // [row 128][k 32], 8 KB/buf
    __shared__ unsigned short lB[2][128 * 32];

    const int srow  = tid >> 2;                      // 0..63 (+64 for 2nd call)
    const int sslot = (tid & 3) ^ (srow & 3);
    const unsigned short* gA = Mb + ((size_t)n * C + ot + srow) * C + sslot * 8;
    const unsigned short* gB = xT + ((size_t)n * HW + tt + srow) * C + sslot * 8;
    const int wbase = (tid & ~63) * 8;               // wave-uniform LDS ushort idx

#define STAGE(bf, k0) do { \
        gl16(gA + (k0),           &lA[bf][wbase]); \
        gl16(gA + (k0) + 64 * C,  &lA[bf][2048 + wbase]); \
        gl16(gB + (k0),           &lB[bf][wbase]); \
        gl16(gB + (k0) + 64 * C,  &lB[bf][2048 + wbase]); \
    } while (0)

    const int aoff = (wm + l15) * 32 + ((q4 ^ (l15 & 3)) * 8);
    const int boff = (wn + l15) * 32 + ((q4 ^ (l15 & 3)) * 8);

    floatx4 acc[4][4] = {};
    STAGE(0, 0);
    for (int kt = 0; kt < 8; ++kt) {
        __syncthreads();                 // drains vmcnt: buf[kt&1] staged & safe
        const int b = kt & 1;
        if (kt < 7) STAGE(b ^ 1, (kt + 1) * 32);   // async prefetch next tile
        short8 a[4], bb[4];
#pragma unroll
        for (int i = 0; i < 4; ++i) a[i]  = *(const short8*)&lA[b][aoff + i * 512];
#pragma unroll
        for (int j = 0; j < 4; ++j) bb[j] = *(const short8*)&lB[b][boff + j * 512];
#pragma unroll
        for (int i = 0; i < 4; ++i)
#pragma unroll
            for (int j = 0; j < 4; ++j)
                acc[i][j] = __builtin_amdgcn_mfma_f32_16x16x32_bf16(
                    a[i], bb[j], acc[i][j], 0, 0, 0);
    }
#undef STAGE

    const int quad = lane >> 4;
#pragma unroll
    for (int i = 0; i < 4; ++i) {
        const int rowb = ot + wm + i * 16 + quad * 4;
#pragma unroll
        for (int r = 0; r < 4; ++r) {
            const int row = rowb + r;
            const float cv = cvec[n * C + row];
            unsigned short* orow = p16 + ((size_t)n * C + row) * HW + tt + wn + l15;
            const float v0 = acc[i][0][r] + cv;
            const float v1 = acc[i][1][r] + cv;
            const float v2 = acc[i][2][r] + cv;
            const float v3 = acc[i][3][r] + cv;
            orow[0]  = f2h(v0);
            orow[16] = f2h(v1);
            orow[32] = f2h(v2);
            orow[48] = f2h(v3);
            float s0 = v0 + v1 + v2 + v3;
            float s1 = v0 * v0 + v1 * v1 + v2 * v2 + v3 * v3;
#pragma unroll
            for (int off = 1; off < 16; off <<= 1) {
                s0 += __shfl_xor(s0, off, 64);
                s1 += __shfl_xor(s1, off, 64);
            }
            if (l15 == 0) {
                atomicAdd(&bsum[n * C + row], s0);
                atomicAdd(&bsq [n * C + row], s1);
            }
        }
    }
}

// ---------------------------------------------------------------------------
// K5-fallback: fp32 SGEMM (no atomics) if ws too small for xT.
#define BM 64
#define BN 64
#define BK 16
__global__ __launch_bounds__(256) void k_gemm_f32(const float* __restrict__ x,
        const float* __restrict__ M, const float* __restrict__ cvec,
        float* __restrict__ pout) {
    const int n  = blockIdx.y;
    const int ot = (blockIdx.x >> 6) * BM;
    const int tt = (blockIdx.x & 63) * BN;
    const float* Mb = M + (size_t)n * C * C;
    const float* xb = x + (size_t)n * C * HW;
    __shared__ float sA[BK][BM];
    __shared__ float sB[BK][BN];
    const int tid = threadIdx.x;
    const int ty = tid >> 4, tx = tid & 15;
    float acc[4][4] = {};
    for (int k0 = 0; k0 < C; k0 += BK) {
        {
            int row = tid >> 2, kq = (tid & 3) << 2;
            const float4 v = *(const float4*)&Mb[(size_t)(ot + row) * C + k0 + kq];
            sA[kq + 0][row] = v.x; sA[kq + 1][row] = v.y;
            sA[kq + 2][row] = v.z; sA[kq + 3][row] = v.w;
        }
        {
            int krow = tid >> 4, tq2 = (tid & 15) << 2;
            const float4 v = *(const float4*)&xb[(size_t)(k0 + krow) * HW + tt + tq2];
            *(float4*)&sB[krow][tq2] = v;
        }
        __syncthreads();
#pragma unroll
        for (int kk = 0; kk < BK; ++kk) {
            float a[4], b[4];
#pragma unroll
            for (int i = 0; i < 4; ++i) a[i] = sA[kk][ty * 4 + i];
#pragma unroll
            for (int j = 0; j < 4; ++j) b[j] = sB[kk][tx * 4 + j];
#pragma unroll
            for (int i = 0; i < 4; ++i)
#pragma unroll
                for (int j = 0; j < 4; ++j) acc[i][j] += a[i] * b[j];
        }
        __syncthreads();
    }
#pragma unroll
    for (int i = 0; i < 4; ++i) {
        const int o = ot + ty * 4 + i;
        const float cv = cvec[n * C + o];
        float4 v;
        v.x = acc[i][0] + cv; v.y = acc[i][1] + cv;
        v.z = acc[i][2] + cv; v.w = acc[i][3] + cv;
        *(float4*)&pout[((size_t)n * C + o) * HW + tt + tx * 4] = v;
    }
}

// ---------------------------------------------------------------------------
// K6 (fallback path only): per-channel BN stats -> scale/shift.
__global__ __launch_bounds__(256) void k_bnstat(const float* __restrict__ p,
        const float* __restrict__ gamma, const float* __restrict__ beta,
        float* __restrict__ scale, float* __restrict__ shift) {
    const int o = blockIdx.x;
    float s0 = 0.f, s1 = 0.f;
    for (int n = 0; n < NB; ++n) {
        const float4* pp = (const float4*)(p + ((size_t)n * C + o) * HW);
        for (int i = threadIdx.x; i < HW / 4; i += 256) {
            const float4 v = pp[i];
            s0 += v.x + v.y + v.z + v.w;
            s1 += v.x * v.x + v.y * v.y + v.z * v.z + v.w * v.w;
        }
    }
    for (int off = 32; off; off >>= 1) {
        s0 += __shfl_down(s0, off, 64);
        s1 += __shfl_down(s1, off, 64);
    }
    __shared__ float r0[4], r1[4];
    if ((threadIdx.x & 63) == 0) { r0[threadIdx.x >> 6] = s0; r1[threadIdx.x >> 6] = s1; }
    __syncthreads();
    if (threadIdx.x == 0) {
        const float S0 = r0[0] + r0[1] + r0[2] + r0[3];
        const float S1 = r1[0] + r1[1] + r1[2] + r1[3];
        const float mean = S0 * (1.f / (float)NHW);
        const float var  = S1 * (1.f / (float)NHW) - mean * mean;
        const float sc   = gamma[o] * rsqrtf(var + 1e-5f);
        scale[o] = sc;
        shift[o] = beta[o] - mean * sc;
    }
}

// ---------------------------------------------------------------------------
// K6': reduce per-(n,o) GEMM partials -> scale/shift. 1 block, 256 threads.
__global__ __launch_bounds__(256) void k_scale(const float* __restrict__ bsum,
        const float* __restrict__ bsq,
        const float* __restrict__ gamma, const float* __restrict__ beta,
        float* __restrict__ scale, float* __restrict__ shift) {
    const int o = threadIdx.x;
    float S0 = 0.f, S1 = 0.f;
    for (int n = 0; n < NB; ++n) {
        S0 += bsum[n * C + o];
        S1 += bsq [n * C + o];
    }
    const float mean = S0 * (1.f / (float)NHW);
    const float var  = S1 * (1.f / (float)NHW) - mean * mean;
    const float sc   = gamma[o] * rsqrtf(var + 1e-5f);
    scale[o] = sc;
    shift[o] = beta[o] - mean * sc;
}

// ---------------------------------------------------------------------------
// K7: out = x + scale[c]*p16 + shift[c]   (p16 fp16 in ws, out written fresh)
__global__ __launch_bounds__(256) void k_final16(const float* __restrict__ x,
        const unsigned short* __restrict__ p16, float* __restrict__ out,
        const float* __restrict__ scale, const float* __restrict__ shift) {
    const size_t total8 = (size_t)NB * C * HW / 8;
    size_t i = (size_t)blockIdx.x * 256 + threadIdx.x;
    const size_t stride = (size_t)gridDim.x * 256;
    for (; i < total8; i += stride) {
        const int c = (int)((i >> 9) & 255);
        const float sc = scale[c], sh = shift[c];
        const short8 pv = ((const short8*)p16)[i];
        const float4 x0 = ((const float4*)x)[2 * i];
        const float4 x1 = ((const float4*)x)[2 * i + 1];
        float4 r0, r1;
        r0.x = x0.x + sc * h2f((unsigned short)pv[0]) + sh;
        r0.y = x0.y + sc * h2f((unsigned short)pv[1]) + sh;
        r0.z = x0.z + sc * h2f((unsigned short)pv[2]) + sh;
        r0.w = x0.w + sc * h2f((unsigned short)pv[3]) + sh;
        r1.x = x1.x + sc * h2f((unsigned short)pv[4]) + sh;
        r1.y = x1.y + sc * h2f((unsigned short)pv[5]) + sh;
        r1.z = x1.z + sc * h2f((unsigned short)pv[6]) + sh;
        r1.w = x1.w + sc * h2f((unsigned short)pv[7]) + sh;
        ((float4*)out)[2 * i]     = r0;
        ((float4*)out)[2 * i + 1] = r1;
    }
}

// K7-fallback: out = x + scale[c]*p + shift[c]  (in-place on d_out holding fp32 p)
__global__ __launch_bounds__(256) void k_final32(const float* __restrict__ x,
        float* __restrict__ out, const float* __restrict__ scale,
        const float* __restrict__ shift) {
    const size_t total4 = (size_t)NB * C * HW / 4;
    size_t i = (size_t)blockIdx.x * 256 + threadIdx.x;
    const size_t stride = (size_t)gridDim.x * 256;
    for (; i < total4; i += stride) {
        const int c = (int)((i >> 10) & 255);
        const float sc = scale[c], sh = shift[c];
        const float4 xv = ((const float4*)x)[i];
        const float4 pv = ((float4*)out)[i];
        float4 r;
        r.x = xv.x + sc * pv.x + sh;
        r.y = xv.y + sc * pv.y + sh;
        r.z = xv.z + sc * pv.z + sh;
        r.w = xv.w + sc * pv.w + sh;
        ((float4*)out)[i] = r;
    }
}

// fallback channel-sum kernel (only used when ws is too small for xT)
__global__ __launch_bounds__(256) void k_colsum(const float* __restrict__ x,
                                                float* __restrict__ s) {
    const int bc = blockIdx.x;
    const float4* p4 = (const float4*)(x + (size_t)bc * HW);
    const int tid = threadIdx.x;
    float acc = 0.f;
    for (int i = tid; i < HW / 4; i += 256) {
        const float4 v = p4[i];
        acc += v.x + v.y + v.z + v.w;
    }
    for (int off = 32; off; off >>= 1) acc += __shfl_down(acc, off, 64);
    __shared__ float red[4];
    if ((tid & 63) == 0) red[tid >> 6] = acc;
    __syncthreads();
    if (tid == 0) atomicAdd(&s[bc], red[0] + red[1] + red[2] + red[3]);
}

// ---------------------------------------------------------------------------
extern "C" void kernel_launch(void* const* d_in, const int* in_sizes, int n_in,
                              void* d_out, int out_size, void* d_ws, size_t ws_size,
                              hipStream_t stream) {
    const float* x       = (const float*)d_in[0];
    const float* w_theta = (const float*)d_in[1];
    const float* b_theta = (const float*)d_in[2];
    const float* w_phi   = (const float*)d_in[3];
    const float* b_phi   = (const float*)d_in[4];
    const float* w_g     = (const float*)d_in[5];
    const float* b_g     = (const float*)d_in[6];
    const float* w_out   = (const float*)d_in[7];
    const float* b_out   = (const float*)d_in[8];
    const float* gamma   = (const float*)d_in[9];
    const float* beta    = (const float*)d_in[10];
    float* out = (float*)d_out;
    float* ws  = (float*)d_ws;

    // workspace layout (float offsets)
    float* s     = ws;                       // 8192
    float* bsum  = s + NB * C;               // 8192  (BN Σp partials per n,o)
    float* bsq   = bsum + NB * C;            // 8192  (BN Σp² partials per n,o)
    float* th    = bsq + NB * C;             // 4096
    float* ph    = th + NB * CI;             // 4096
    float* pm    = ph + NB * CI;             // 64
    float* A     = pm + NB * 2;              // 524288
    float* q     = A + (size_t)NB * CI * CI; // 4096
    float* W     = q + NB * CI;              // 1048576
    float* M     = W + (size_t)NB * C * CI;  // 2097152
    float* cvec  = M + (size_t)NB * C * C;   // 8192
    float* scale = cvec + NB * C;            // 256
    float* shift = scale + C;                // 256
    unsigned short* Mb16 = (unsigned short*)(shift + C);          // 2097152 u16
    unsigned short* xT   = Mb16 + (size_t)NB * C * C;             // 33554432 u16
    unsigned short* p16  = xT + (size_t)NB * HW * C;              // 33554432 u16
    const size_t need_bytes =
        ((char*)(p16 + (size_t)NB * C * HW) - (char*)ws);
    const bool use_mfma = (ws_size >= need_bytes);

    hipMemsetAsync(s, 0, 3 * NB * C * sizeof(float), stream);  // s + bsum + bsq
    if (use_mfma) {
        k_prep<<<dim3(64, 4, NB), 256, 0, stream>>>(x, xT, s);
    } else {
        k_colsum<<<NB * C, 256, 0, stream>>>(x, s);
    }
    k_thph<<<NB, CI, 0, stream>>>(s, w_theta, b_theta, w_phi, b_phi, th, ph, pm);
    k_arow<<<NB * CI, 64, 0, stream>>>(th, ph, pm, b_g, A, q);
    k_W<<<NB * C, CI, 0, stream>>>(w_out, A, q, b_out, W, cvec);
    k_M<<<NB * 16, 256, 0, stream>>>(W, w_g, M, use_mfma ? Mb16 : (unsigned short*)nullptr);
    if (use_mfma) {
        k_gemm_mfma<<<dim3(64, NB), 256, 0, stream>>>(xT, Mb16, cvec, p16, bsum, bsq);
        k_scale<<<1, 256, 0, stream>>>(bsum, bsq, gamma, beta, scale, shift);
        k_final16<<<16384, 256, 0, stream>>>(x, p16, out, scale, shift);
    } else {
        k_gemm_f32<<<dim3(256, NB), 256, 0, stream>>>(x, M, cvec, out);
        k_bnstat<<<C, 256, 0, stream>>>(out, gamma, beta, scale, shift);
        k_final32<<<32768, 256, 0, stream>>>(x, out, scale, shift);
    }
}

// Round 5
// 407.758 us; speedup vs baseline: 1.0898x; 1.0187x over previous
//
#include <hip/hip_runtime.h>
#include <hip/hip_bf16.h>

#define NB   32
#define C    256
#define CI   128
#define HW   4096
#define NHW  131072

typedef __attribute__((ext_vector_type(8))) short short8;
typedef __attribute__((ext_vector_type(4))) float floatx4;

__device__ __forceinline__ unsigned short f2bf(float f) {
    unsigned int u = __float_as_uint(f);
    return (unsigned short)((u + 0x7fffu + ((u >> 16) & 1u)) >> 16);
}
__device__ __forceinline__ unsigned short f2h(float f) {
    _Float16 h = (_Float16)f;
    return __builtin_bit_cast(unsigned short, h);
}
__device__ __forceinline__ float h2f(unsigned short u) {
    _Float16 h = __builtin_bit_cast(_Float16, u);
    return (float)h;
}

// async global->LDS, 16B per lane, wave-uniform LDS base + lane*16
__device__ __forceinline__ void gl16(const void* g, void* l) {
    __builtin_amdgcn_global_load_lds(
        (const __attribute__((address_space(1))) unsigned int*)g,
        (__attribute__((address_space(3))) unsigned int*)l, 16, 0, 0);
}

// ---------------------------------------------------------------------------
// K0: fused cast+transpose (x fp32 [n][c][t] -> xT bf16 [n][t][c]) + channel sums.
// grid (64 t-tiles, 4 c-tiles, 32 n), block 256.
__global__ __launch_bounds__(256) void k_prep(const float* __restrict__ x,
        unsigned short* __restrict__ xT, float* __restrict__ s) {
    const int n = blockIdx.z, c0 = blockIdx.y * 64, t0 = blockIdx.x * 64;
    __shared__ float sA[64][68];
    const int tid = threadIdx.x;
    const int cr = tid >> 4;          // 0..15
    const int tq = (tid & 15) * 4;    // 0..60
#pragma unroll
    for (int pass = 0; pass < 4; ++pass) {
        const int c = cr + pass * 16;
        const float4 v = *(const float4*)&x[((size_t)n * C + c0 + c) * HW + t0 + tq];
        const int swz = ((c >> 3) & 7) * 8;
        *(float4*)&sA[c][tq ^ swz] = v;
        float ps = v.x + v.y + v.z + v.w;
        for (int off = 1; off < 16; off <<= 1) ps += __shfl_xor(ps, off, 64);
        if ((tid & 15) == 0) atomicAdd(&s[n * C + c0 + c], ps);
    }
    __syncthreads();
    // write xT rows: 32 t-rows per pass, 8 threads/row, 8 c each
    const int tr = tid >> 3;          // 0..31
    const int cc = (tid & 7) * 8;     // 0..56
#pragma unroll
    for (int pass = 0; pass < 2; ++pass) {
        const int t = tr + pass * 32;
        unsigned int w[4];
#pragma unroll
        for (int jj = 0; jj < 4; ++jj) {
            const int ca = cc + 2 * jj, cb = cc + 2 * jj + 1;
            unsigned short lo = f2bf(sA[ca][t ^ (((ca >> 3) & 7) * 8)]);
            unsigned short hi = f2bf(sA[cb][t ^ (((cb >> 3) & 7) * 8)]);
            w[jj] = (unsigned int)lo | ((unsigned int)hi << 16);
        }
        uint4 u4; u4.x = w[0]; u4.y = w[1]; u4.z = w[2]; u4.w = w[3];
        *(uint4*)&xT[((size_t)n * HW + t0 + t) * C + c0 + cc] = u4;
    }
}

// ---------------------------------------------------------------------------
// K1: theta/phi vectors. REWRITTEN: coalesced (lanes on c, 256B wave-loads)
// and parallel (grid NB*8, 16 d per block, 4 waves). pm logic moved to k_arow.
// Old version: 32 blocks, lanes on d -> 1KB-stride loads (64 lines/wave-load).
__global__ __launch_bounds__(256) void k_thph(const float* __restrict__ s,
        const float* __restrict__ w_theta, const float* __restrict__ b_theta,
        const float* __restrict__ w_phi,  const float* __restrict__ b_phi,
        float* __restrict__ th, float* __restrict__ ph) {
    const int n = blockIdx.x >> 3, d0 = (blockIdx.x & 7) * 16;
    const int tid = threadIdx.x, wv = tid >> 6, lane = tid & 63;
    __shared__ float sv[C];
    sv[tid] = s[n * C + tid] * (1.f / 16.f);
    __syncthreads();
#pragma unroll
    for (int k = 0; k < 4; ++k) {
        const int d = d0 + wv * 4 + k;
        const float* wt = w_theta + (size_t)d * C;
        const float* wp = w_phi   + (size_t)d * C;
        float a = 0.f, b = 0.f;
#pragma unroll
        for (int cc = 0; cc < C; cc += 64) {
            const float svv = sv[cc + lane];
            a += wt[cc + lane] * svv;
            b += wp[cc + lane] * svv;
        }
        for (int off = 32; off; off >>= 1) {
            a += __shfl_xor(a, off, 64);
            b += __shfl_xor(b, off, 64);
        }
        if (lane == 0) {
            th[n * CI + d] = (a + 256.f * b_theta[d]) * 0.08838834764831845f;
            ph[n * CI + d] = b + 256.f * b_phi[d];
        }
    }
}

// ---------------------------------------------------------------------------
// K2: one softmax row of A per one-wave block. grid NB*CI, block 64.
// Now computes ph max/min in-wave (12 shuffles) instead of reading pm.
__global__ __launch_bounds__(64) void k_arow(const float* __restrict__ th,
        const float* __restrict__ ph, const float* __restrict__ b_g,
        float* __restrict__ A, float* __restrict__ q) {
    const int n = blockIdx.x >> 7, c = blockIdx.x & 127, lane = threadIdx.x;
    const float thc = th[n * CI + c];
    const float2 phv = *(const float2*)&ph[n * CI + lane * 2];
    float pmax = fmaxf(phv.x, phv.y), pmin = fminf(phv.x, phv.y);
    for (int off = 32; off; off >>= 1) {
        pmax = fmaxf(pmax, __shfl_xor(pmax, off, 64));
        pmin = fminf(pmin, __shfl_xor(pmin, off, 64));
    }
    const float m = (thc >= 0.f) ? thc * pmax : thc * pmin;
    float e0 = __expf(thc * phv.x - m);
    float e1 = __expf(thc * phv.y - m);
    float z = e0 + e1;
    for (int off = 32; off; off >>= 1) z += __shfl_xor(z, off, 64);
    const float inv = 1.f / z;
    e0 *= inv; e1 *= inv;
    float2 av; av.x = e0; av.y = e1;
    *(float2*)&A[((size_t)n * CI + c) * CI + lane * 2] = av;
    const float2 bg = *(const float2*)&b_g[lane * 2];
    float qv = e0 * bg.x + e1 * bg.y;
    for (int off = 32; off; off >>= 1) qv += __shfl_xor(qv, off, 64);
    if (lane == 0) q[n * CI + c] = qv;
}

// ---------------------------------------------------------------------------
// K3: W_n[o,d] = sum_c w_out[o,c] * A_n[c,d];  cvec[n,o] = w_out[o,:].q_n + b_out[o]
__global__ __launch_bounds__(128) void k_W(const float* __restrict__ w_out,
        const float* __restrict__ A, const float* __restrict__ q,
        const float* __restrict__ b_out,
        float* __restrict__ W, float* __restrict__ cvec) {
    const int n = blockIdx.x >> 8, o = blockIdx.x & 255, d = threadIdx.x;
    float acc = 0.f;
    for (int c = 0; c < CI; ++c)
        acc += w_out[o * CI + c] * A[((size_t)n * CI + c) * CI + d];
    W[((size_t)n * C + o) * CI + d] = acc;
    if (d == 0) {
        float cv = 0.f;
        for (int c = 0; c < CI; ++c) cv += w_out[o * CI + c] * q[n * CI + c];
        cvec[n * C + o] = cv + b_out[o];
    }
}

// ---------------------------------------------------------------------------
// K4: M_n[o,c2] = sum_d W_n[o,d] * w_g[d,c2]  (fp32 + bf16 copies)
// 16 o-rows per block so w_g streams once per block.
__global__ __launch_bounds__(256) void k_M(const float* __restrict__ W,
        const float* __restrict__ w_g, float* __restrict__ M,
        unsigned short* __restrict__ Mb16) {
    const int n = blockIdx.x >> 4, o0 = (blockIdx.x & 15) * 16;
    const int tid = threadIdx.x, c2 = tid;
    __shared__ float sWt[CI][20];
    for (int idx = tid; idx < 16 * CI; idx += 256) {
        const int oo = idx >> 7, d = idx & 127;
        sWt[d][oo] = W[((size_t)n * C + o0 + oo) * CI + d];
    }
    __syncthreads();
    float acc[16] = {};
    for (int d = 0; d < CI; ++d) {
        const float g = w_g[d * C + c2];
        const float4 w0 = *(const float4*)&sWt[d][0];
        const float4 w1 = *(const float4*)&sWt[d][4];
        const float4 w2 = *(const float4*)&sWt[d][8];
        const float4 w3 = *(const float4*)&sWt[d][12];
        acc[0]  += w0.x * g;  acc[1]  += w0.y * g;
        acc[2]  += w0.z * g;  acc[3]  += w0.w * g;
        acc[4]  += w1.x * g;  acc[5]  += w1.y * g;
        acc[6]  += w1.z * g;  acc[7]  += w1.w * g;
        acc[8]  += w2.x * g;  acc[9]  += w2.y * g;
        acc[10] += w2.z * g;  acc[11] += w2.w * g;
        acc[12] += w3.x * g;  acc[13] += w3.y * g;
        acc[14] += w3.z * g;  acc[15] += w3.w * g;
    }
    float* Mp = M + ((size_t)n * C + o0) * C + c2;
#pragma unroll
    for (int oo = 0; oo < 16; ++oo) Mp[(size_t)oo * C] = acc[oo];
    if (Mb16) {
        unsigned short* Mbp = Mb16 + ((size_t)n * C + o0) * C + c2;
#pragma unroll
        for (int oo = 0; oo < 16; ++oo) Mbp[(size_t)oo * C] = f2bf(acc[oo]);
    }
}

// ---------------------------------------------------------------------------
// K5: MFMA GEMM  p[n] = M_n @ x[n] + cvec, fp16 out to ws p16.
// LDS-staged, double-buffered (global_load_lds width=16), BK=32, 128x128 tile.
// Epilogue accumulates per-(n,channel) BN partials (sum p, sum p^2) in fp32.
__global__ __launch_bounds__(256, 4) void k_gemm_mfma(
        const unsigned short* __restrict__ xT,   // [n][4096][256] bf16
        const unsigned short* __restrict__ Mb,   // [n][256][256] bf16
        const float* __restrict__ cvec,
        unsigned short* __restrict__ p16,        // [n][256][4096] fp16
        float* __restrict__ bsum, float* __restrict__ bsq) {
    const int n  = blockIdx.y;
    const int tt = (blockIdx.x & 31) * 128;
    const int ot = (blockIdx.x >> 5) * 128;
    const int tid = threadIdx.x;
    const int wave = tid >> 6, lane = tid & 63;
    const int wm = (wave >> 1) * 64, wn = (wave & 1) * 64;
    const int l15 = lane & 15, q4 = lane >> 4;   // logical 16B k-slot 0..3

    __shared__ unsigned short lA[2][128 * 32];   // [row 128][k 32], 8 KB/buf
    __shared__ unsigned short lB[2][128 * 32];

    const int srow  = tid >> 2;                      // 0..63 (+64 for 2nd call)
    const int sslot = (tid & 3) ^ (srow & 3);
    const unsigned short* gA = Mb + ((size_t)n * C + ot + srow) * C + sslot * 8;
    const unsigned short* gB = xT + ((size_t)n * HW + tt + srow) * C + sslot * 8;
    const int wbase = (tid & ~63) * 8;               // wave-uniform LDS ushort idx

#define STAGE(bf, k0) do { \
        gl16(gA + (k0),           &lA[bf][wbase]); \
        gl16(gA + (k0) + 64 * C,  &lA[bf][2048 + wbase]); \
        gl16(gB + (k0),           &lB[bf][wbase]); \
        gl16(gB + (k0) + 64 * C,  &lB[bf][2048 + wbase]); \
    } while (0)

    const int aoff = (wm + l15) * 32 + ((q4 ^ (l15 & 3)) * 8);
    const int boff = (wn + l15) * 32 + ((q4 ^ (l15 & 3)) * 8);

    floatx4 acc[4][4] = {};
    STAGE(0, 0);
    for (int kt = 0; kt < 8; ++kt) {
        __syncthreads();                 // drains vmcnt: buf[kt&1] staged & safe
        const int b = kt & 1;
        if (kt < 7) STAGE(b ^ 1, (kt + 1) * 32);   // async prefetch next tile
        short8 a[4], bb[4];
#pragma unroll
        for (int i = 0; i < 4; ++i) a[i]  = *(const short8*)&lA[b][aoff + i * 512];
#pragma unroll
        for (int j = 0; j < 4; ++j) bb[j] = *(const short8*)&lB[b][boff + j * 512];
#pragma unroll
        for (int i = 0; i < 4; ++i)
#pragma unroll
            for (int j = 0; j < 4; ++j)
                acc[i][j] = __builtin_amdgcn_mfma_f32_16x16x32_bf16(
                    a[i], bb[j], acc[i][j], 0, 0, 0);
    }
#undef STAGE

    const int quad = lane >> 4;
#pragma unroll
    for (int i = 0; i < 4; ++i) {
        const int rowb = ot + wm + i * 16 + quad * 4;
#pragma unroll
        for (int r = 0; r < 4; ++r) {
            const int row = rowb + r;
            const float cv = cvec[n * C + row];
            unsigned short* orow = p16 + ((size_t)n * C + row) * HW + tt + wn + l15;
            const float v0 = acc[i][0][r] + cv;
            const float v1 = acc[i][1][r] + cv;
            const float v2 = acc[i][2][r] + cv;
            const float v3 = acc[i][3][r] + cv;
            orow[0]  = f2h(v0);
            orow[16] = f2h(v1);
            orow[32] = f2h(v2);
            orow[48] = f2h(v3);
            float s0 = v0 + v1 + v2 + v3;
            float s1 = v0 * v0 + v1 * v1 + v2 * v2 + v3 * v3;
#pragma unroll
            for (int off = 1; off < 16; off <<= 1) {
                s0 += __shfl_xor(s0, off, 64);
                s1 += __shfl_xor(s1, off, 64);
            }
            if (l15 == 0) {
                atomicAdd(&bsum[n * C + row], s0);
                atomicAdd(&bsq [n * C + row], s1);
            }
        }
    }
}

// ---------------------------------------------------------------------------
// K5-fallback: fp32 SGEMM (no atomics) if ws too small for xT.
#define BM 64
#define BN 64
#define BK 16
__global__ __launch_bounds__(256) void k_gemm_f32(const float* __restrict__ x,
        const float* __restrict__ M, const float* __restrict__ cvec,
        float* __restrict__ pout) {
    const int n  = blockIdx.y;
    const int ot = (blockIdx.x >> 6) * BM;
    const int tt = (blockIdx.x & 63) * BN;
    const float* Mb = M + (size_t)n * C * C;
    const float* xb = x + (size_t)n * C * HW;
    __shared__ float sA[BK][BM];
    __shared__ float sB[BK][BN];
    const int tid = threadIdx.x;
    const int ty = tid >> 4, tx = tid & 15;
    float acc[4][4] = {};
    for (int k0 = 0; k0 < C; k0 += BK) {
        {
            int row = tid >> 2, kq = (tid & 3) << 2;
            const float4 v = *(const float4*)&Mb[(size_t)(ot + row) * C + k0 + kq];
            sA[kq + 0][row] = v.x; sA[kq + 1][row] = v.y;
            sA[kq + 2][row] = v.z; sA[kq + 3][row] = v.w;
        }
        {
            int krow = tid >> 4, tq2 = (tid & 15) << 2;
            const float4 v = *(const float4*)&xb[(size_t)(k0 + krow) * HW + tt + tq2];
            *(float4*)&sB[krow][tq2] = v;
        }
        __syncthreads();
#pragma unroll
        for (int kk = 0; kk < BK; ++kk) {
            float a[4], b[4];
#pragma unroll
            for (int i = 0; i < 4; ++i) a[i] = sA[kk][ty * 4 + i];
#pragma unroll
            for (int j = 0; j < 4; ++j) b[j] = sB[kk][tx * 4 + j];
#pragma unroll
            for (int i = 0; i < 4; ++i)
#pragma unroll
                for (int j = 0; j < 4; ++j) acc[i][j] += a[i] * b[j];
        }
        __syncthreads();
    }
#pragma unroll
    for (int i = 0; i < 4; ++i) {
        const int o = ot + ty * 4 + i;
        const float cv = cvec[n * C + o];
        float4 v;
        v.x = acc[i][0] + cv; v.y = acc[i][1] + cv;
        v.z = acc[i][2] + cv; v.w = acc[i][3] + cv;
        *(float4*)&pout[((size_t)n * C + o) * HW + tt + tx * 4] = v;
    }
}

// ---------------------------------------------------------------------------
// K6 (fallback path only): per-channel BN stats -> scale/shift.
__global__ __launch_bounds__(256) void k_bnstat(const float* __restrict__ p,
        const float* __restrict__ gamma, const float* __restrict__ beta,
        float* __restrict__ scale, float* __restrict__ shift) {
    const int o = blockIdx.x;
    float s0 = 0.f, s1 = 0.f;
    for (int n = 0; n < NB; ++n) {
        const float4* pp = (const float4*)(p + ((size_t)n * C + o) * HW);
        for (int i = threadIdx.x; i < HW / 4; i += 256) {
            const float4 v = pp[i];
            s0 += v.x + v.y + v.z + v.w;
            s1 += v.x * v.x + v.y * v.y + v.z * v.z + v.w * v.w;
        }
    }
    for (int off = 32; off; off >>= 1) {
        s0 += __shfl_down(s0, off, 64);
        s1 += __shfl_down(s1, off, 64);
    }
    __shared__ float r0[4], r1[4];
    if ((threadIdx.x & 63) == 0) { r0[threadIdx.x >> 6] = s0; r1[threadIdx.x >> 6] = s1; }
    __syncthreads();
    if (threadIdx.x == 0) {
        const float S0 = r0[0] + r0[1] + r0[2] + r0[3];
        const float S1 = r1[0] + r1[1] + r1[2] + r1[3];
        const float mean = S0 * (1.f / (float)NHW);
        const float var  = S1 * (1.f / (float)NHW) - mean * mean;
        const float sc   = gamma[o] * rsqrtf(var + 1e-5f);
        scale[o] = sc;
        shift[o] = beta[o] - mean * sc;
    }
}

// ---------------------------------------------------------------------------
// K6': reduce per-(n,o) GEMM partials -> scale/shift. 1 block, 256 threads.
__global__ __launch_bounds__(256) void k_scale(const float* __restrict__ bsum,
        const float* __restrict__ bsq,
        const float* __restrict__ gamma, const float* __restrict__ beta,
        float* __restrict__ scale, float* __restrict__ shift) {
    const int o = threadIdx.x;
    float S0 = 0.f, S1 = 0.f;
    for (int n = 0; n < NB; ++n) {
        S0 += bsum[n * C + o];
        S1 += bsq [n * C + o];
    }
    const float mean = S0 * (1.f / (float)NHW);
    const float var  = S1 * (1.f / (float)NHW) - mean * mean;
    const float sc   = gamma[o] * rsqrtf(var + 1e-5f);
    scale[o] = sc;
    shift[o] = beta[o] - mean * sc;
}

// ---------------------------------------------------------------------------
// K7: out = x + scale[c]*p16 + shift[c]   (p16 fp16 in ws, out written fresh)
__global__ __launch_bounds__(256) void k_final16(const float* __restrict__ x,
        const unsigned short* __restrict__ p16, float* __restrict__ out,
        const float* __restrict__ scale, const float* __restrict__ shift) {
    const size_t total8 = (size_t)NB * C * HW / 8;
    size_t i = (size_t)blockIdx.x * 256 + threadIdx.x;
    const size_t stride = (size_t)gridDim.x * 256;
    for (; i < total8; i += stride) {
        const int c = (int)((i >> 9) & 255);
        const float sc = scale[c], sh = shift[c];
        const short8 pv = ((const short8*)p16)[i];
        const float4 x0 = ((const float4*)x)[2 * i];
        const float4 x1 = ((const float4*)x)[2 * i + 1];
        float4 r0, r1;
        r0.x = x0.x + sc * h2f((unsigned short)pv[0]) + sh;
        r0.y = x0.y + sc * h2f((unsigned short)pv[1]) + sh;
        r0.z = x0.z + sc * h2f((unsigned short)pv[2]) + sh;
        r0.w = x0.w + sc * h2f((unsigned short)pv[3]) + sh;
        r1.x = x1.x + sc * h2f((unsigned short)pv[4]) + sh;
        r1.y = x1.y + sc * h2f((unsigned short)pv[5]) + sh;
        r1.z = x1.z + sc * h2f((unsigned short)pv[6]) + sh;
        r1.w = x1.w + sc * h2f((unsigned short)pv[7]) + sh;
        ((float4*)out)[2 * i]     = r0;
        ((float4*)out)[2 * i + 1] = r1;
    }
}

// K7-fallback: out = x + scale[c]*p + shift[c]  (in-place on d_out holding fp32 p)
__global__ __launch_bounds__(256) void k_final32(const float* __restrict__ x,
        float* __restrict__ out, const float* __restrict__ scale,
        const float* __restrict__ shift) {
    const size_t total4 = (size_t)NB * C * HW / 4;
    size_t i = (size_t)blockIdx.x * 256 + threadIdx.x;
    const size_t stride = (size_t)gridDim.x * 256;
    for (; i < total4; i += stride) {
        const int c = (int)((i >> 10) & 255);
        const float sc = scale[c], sh = shift[c];
        const float4 xv = ((const float4*)x)[i];
        const float4 pv = ((float4*)out)[i];
        float4 r;
        r.x = xv.x + sc * pv.x + sh;
        r.y = xv.y + sc * pv.y + sh;
        r.z = xv.z + sc * pv.z + sh;
        r.w = xv.w + sc * pv.w + sh;
        ((float4*)out)[i] = r;
    }
}

// fallback channel-sum kernel (only used when ws is too small for xT)
__global__ __launch_bounds__(256) void k_colsum(const float* __restrict__ x,
                                                float* __restrict__ s) {
    const int bc = blockIdx.x;
    const float4* p4 = (const float4*)(x + (size_t)bc * HW);
    const int tid = threadIdx.x;
    float acc = 0.f;
    for (int i = tid; i < HW / 4; i += 256) {
        const float4 v = p4[i];
        acc += v.x + v.y + v.z + v.w;
    }
    for (int off = 32; off; off >>= 1) acc += __shfl_down(acc, off, 64);
    __shared__ float red[4];
    if ((tid & 63) == 0) red[tid >> 6] = acc;
    __syncthreads();
    if (tid == 0) atomicAdd(&s[bc], red[0] + red[1] + red[2] + red[3]);
}

// ---------------------------------------------------------------------------
extern "C" void kernel_launch(void* const* d_in, const int* in_sizes, int n_in,
                              void* d_out, int out_size, void* d_ws, size_t ws_size,
                              hipStream_t stream) {
    const float* x       = (const float*)d_in[0];
    const float* w_theta = (const float*)d_in[1];
    const float* b_theta = (const float*)d_in[2];
    const float* w_phi   = (const float*)d_in[3];
    const float* b_phi   = (const float*)d_in[4];
    const float* w_g     = (const float*)d_in[5];
    const float* b_g     = (const float*)d_in[6];
    const float* w_out   = (const float*)d_in[7];
    const float* b_out   = (const float*)d_in[8];
    const float* gamma   = (const float*)d_in[9];
    const float* beta    = (const float*)d_in[10];
    float* out = (float*)d_out;
    float* ws  = (float*)d_ws;

    // workspace layout (float offsets)
    float* s     = ws;                       // 8192
    float* bsum  = s + NB * C;               // 8192  (BN Σp partials per n,o)
    float* bsq   = bsum + NB * C;            // 8192  (BN Σp² partials per n,o)
    float* th    = bsq + NB * C;             // 4096
    float* ph    = th + NB * CI;             // 4096
    float* pm    = ph + NB * CI;             // 64 (unused, kept for layout)
    float* A     = pm + NB * 2;              // 524288
    float* q     = A + (size_t)NB * CI * CI; // 4096
    float* W     = q + NB * CI;              // 1048576
    float* M     = W + (size_t)NB * C * CI;  // 2097152
    float* cvec  = M + (size_t)NB * C * C;   // 8192
    float* scale = cvec + NB * C;            // 256
    float* shift = scale + C;                // 256
    unsigned short* Mb16 = (unsigned short*)(shift + C);          // 2097152 u16
    unsigned short* xT   = Mb16 + (size_t)NB * C * C;             // 33554432 u16
    unsigned short* p16  = xT + (size_t)NB * HW * C;              // 33554432 u16
    const size_t need_bytes =
        ((char*)(p16 + (size_t)NB * C * HW) - (char*)ws);
    const bool use_mfma = (ws_size >= need_bytes);

    hipMemsetAsync(s, 0, 3 * NB * C * sizeof(float), stream);  // s + bsum + bsq
    if (use_mfma) {
        k_prep<<<dim3(64, 4, NB), 256, 0, stream>>>(x, xT, s);
    } else {
        k_colsum<<<NB * C, 256, 0, stream>>>(x, s);
    }
    k_thph<<<NB * 8, 256, 0, stream>>>(s, w_theta, b_theta, w_phi, b_phi, th, ph);
    k_arow<<<NB * CI, 64, 0, stream>>>(th, ph, b_g, A, q);
    k_W<<<NB * C, CI, 0, stream>>>(w_out, A, q, b_out, W, cvec);
    k_M<<<NB * 16, 256, 0, stream>>>(W, w_g, M, use_mfma ? Mb16 : (unsigned short*)nullptr);
    if (use_mfma) {
        k_gemm_mfma<<<dim3(64, NB), 256, 0, stream>>>(xT, Mb16, cvec, p16, bsum, bsq);
        k_scale<<<1, 256, 0, stream>>>(bsum, bsq, gamma, beta, scale, shift);
        k_final16<<<16384, 256, 0, stream>>>(x, p16, out, scale, shift);
    } else {
        k_gemm_f32<<<dim3(256, NB), 256, 0, stream>>>(x, M, cvec, out);
        k_bnstat<<<C, 256, 0, stream>>>(out, gamma, beta, scale, shift);
        k_final32<<<32768, 256, 0, stream>>>(x, out, scale, shift);
    }
}

// Round 6
// 399.447 us; speedup vs baseline: 1.1124x; 1.0208x over previous
//
#include <hip/hip_runtime.h>
#include <hip/hip_bf16.h>

#define NB   32
#define C    256
#define CI   128
#define HW   4096
#define NHW  131072

typedef __attribute__((ext_vector_type(8))) short short8;
typedef __attribute__((ext_vector_type(4))) float floatx4;

__device__ __forceinline__ unsigned short f2bf(float f) {
    unsigned int u = __float_as_uint(f);
    return (unsigned short)((u + 0x7fffu + ((u >> 16) & 1u)) >> 16);
}
__device__ __forceinline__ unsigned short f2h(float f) {
    _Float16 h = (_Float16)f;
    return __builtin_bit_cast(unsigned short, h);
}
__device__ __forceinline__ float h2f(unsigned short u) {
    _Float16 h = __builtin_bit_cast(_Float16, u);
    return (float)h;
}

// async global->LDS, 16B per lane, wave-uniform LDS base + lane*16
__device__ __forceinline__ void gl16(const void* g, void* l) {
    __builtin_amdgcn_global_load_lds(
        (const __attribute__((address_space(1))) unsigned int*)g,
        (__attribute__((address_space(3))) unsigned int*)l, 16, 0, 0);
}

// ---------------------------------------------------------------------------
// K0: fused cast+transpose (x fp32 [n][c][t] -> xT bf16 [n][t][c]) + channel sums.
// grid (64 t-tiles, 4 c-tiles, 32 n), block 256.
__global__ __launch_bounds__(256) void k_prep(const float* __restrict__ x,
        unsigned short* __restrict__ xT, float* __restrict__ s) {
    const int n = blockIdx.z, c0 = blockIdx.y * 64, t0 = blockIdx.x * 64;
    __shared__ float sA[64][68];
    const int tid = threadIdx.x;
    const int cr = tid >> 4;          // 0..15
    const int tq = (tid & 15) * 4;    // 0..60
#pragma unroll
    for (int pass = 0; pass < 4; ++pass) {
        const int c = cr + pass * 16;
        const float4 v = *(const float4*)&x[((size_t)n * C + c0 + c) * HW + t0 + tq];
        const int swz = ((c >> 3) & 7) * 8;
        *(float4*)&sA[c][tq ^ swz] = v;
        float ps = v.x + v.y + v.z + v.w;
        for (int off = 1; off < 16; off <<= 1) ps += __shfl_xor(ps, off, 64);
        if ((tid & 15) == 0) atomicAdd(&s[n * C + c0 + c], ps);
    }
    __syncthreads();
    // write xT rows: 32 t-rows per pass, 8 threads/row, 8 c each
    const int tr = tid >> 3;          // 0..31
    const int cc = (tid & 7) * 8;     // 0..56
#pragma unroll
    for (int pass = 0; pass < 2; ++pass) {
        const int t = tr + pass * 32;
        unsigned int w[4];
#pragma unroll
        for (int jj = 0; jj < 4; ++jj) {
            const int ca = cc + 2 * jj, cb = cc + 2 * jj + 1;
            unsigned short lo = f2bf(sA[ca][t ^ (((ca >> 3) & 7) * 8)]);
            unsigned short hi = f2bf(sA[cb][t ^ (((cb >> 3) & 7) * 8)]);
            w[jj] = (unsigned int)lo | ((unsigned int)hi << 16);
        }
        uint4 u4; u4.x = w[0]; u4.y = w[1]; u4.z = w[2]; u4.w = w[3];
        *(uint4*)&xT[((size_t)n * HW + t0 + t) * C + c0 + cc] = u4;
    }
}

// ---------------------------------------------------------------------------
// K1: theta/phi vectors. Coalesced (lanes on c) and parallel (grid NB*8).
__global__ __launch_bounds__(256) void k_thph(const float* __restrict__ s,
        const float* __restrict__ w_theta, const float* __restrict__ b_theta,
        const float* __restrict__ w_phi,  const float* __restrict__ b_phi,
        float* __restrict__ th, float* __restrict__ ph) {
    const int n = blockIdx.x >> 3, d0 = (blockIdx.x & 7) * 16;
    const int tid = threadIdx.x, wv = tid >> 6, lane = tid & 63;
    __shared__ float sv[C];
    sv[tid] = s[n * C + tid] * (1.f / 16.f);
    __syncthreads();
#pragma unroll
    for (int k = 0; k < 4; ++k) {
        const int d = d0 + wv * 4 + k;
        const float* wt = w_theta + (size_t)d * C;
        const float* wp = w_phi   + (size_t)d * C;
        float a = 0.f, b = 0.f;
#pragma unroll
        for (int cc = 0; cc < C; cc += 64) {
            const float svv = sv[cc + lane];
            a += wt[cc + lane] * svv;
            b += wp[cc + lane] * svv;
        }
        for (int off = 32; off; off >>= 1) {
            a += __shfl_xor(a, off, 64);
            b += __shfl_xor(b, off, 64);
        }
        if (lane == 0) {
            th[n * CI + d] = (a + 256.f * b_theta[d]) * 0.08838834764831845f;
            ph[n * CI + d] = b + 256.f * b_phi[d];
        }
    }
}

// ---------------------------------------------------------------------------
// K2: one softmax row of A per one-wave block. grid NB*CI, block 64.
// Computes ph max/min in-wave instead of reading pm.
__global__ __launch_bounds__(64) void k_arow(const float* __restrict__ th,
        const float* __restrict__ ph, const float* __restrict__ b_g,
        float* __restrict__ A, float* __restrict__ q) {
    const int n = blockIdx.x >> 7, c = blockIdx.x & 127, lane = threadIdx.x;
    const float thc = th[n * CI + c];
    const float2 phv = *(const float2*)&ph[n * CI + lane * 2];
    float pmax = fmaxf(phv.x, phv.y), pmin = fminf(phv.x, phv.y);
    for (int off = 32; off; off >>= 1) {
        pmax = fmaxf(pmax, __shfl_xor(pmax, off, 64));
        pmin = fminf(pmin, __shfl_xor(pmin, off, 64));
    }
    const float m = (thc >= 0.f) ? thc * pmax : thc * pmin;
    float e0 = __expf(thc * phv.x - m);
    float e1 = __expf(thc * phv.y - m);
    float z = e0 + e1;
    for (int off = 32; off; off >>= 1) z += __shfl_xor(z, off, 64);
    const float inv = 1.f / z;
    e0 *= inv; e1 *= inv;
    float2 av; av.x = e0; av.y = e1;
    *(float2*)&A[((size_t)n * CI + c) * CI + lane * 2] = av;
    const float2 bg = *(const float2*)&b_g[lane * 2];
    float qv = e0 * bg.x + e1 * bg.y;
    for (int off = 32; off; off >>= 1) qv += __shfl_xor(qv, off, 64);
    if (lane == 0) q[n * CI + c] = qv;
}

// ---------------------------------------------------------------------------
// K3: W_n[o,d] = sum_c w_out[o,c] * A_n[c,d];  cvec[n,o] = w_out[o,:].q_n + b_out[o]
// Retiled (same pattern as k_M fix): 16 o-rows per block, grid NB*16 x 128 thr.
// A_n streamed ONCE per block (A-traffic 512 MB -> 32 MB), w_out+q staged in LDS.
__global__ __launch_bounds__(128) void k_W(const float* __restrict__ w_out,
        const float* __restrict__ A, const float* __restrict__ q,
        const float* __restrict__ b_out,
        float* __restrict__ W, float* __restrict__ cvec) {
    const int n = blockIdx.x >> 4, o0 = (blockIdx.x & 15) * 16;
    const int d = threadIdx.x;   // 0..127
    __shared__ float sWo[16][CI];   // w_out tile [oo][c], 8 KB
    __shared__ float sq[CI];
    for (int idx = d; idx < 16 * CI; idx += 128) {
        const int oo = idx >> 7, c = idx & 127;
        sWo[oo][c] = w_out[(o0 + oo) * CI + c];
    }
    sq[d] = q[n * CI + d];
    __syncthreads();
    float acc[16] = {};
    for (int c = 0; c < CI; ++c) {
        const float a = A[((size_t)n * CI + c) * CI + d];   // coalesced 512B row
#pragma unroll
        for (int oo = 0; oo < 16; ++oo) acc[oo] += sWo[oo][c] * a;  // LDS broadcast
    }
#pragma unroll
    for (int oo = 0; oo < 16; ++oo)
        W[((size_t)n * C + o0 + oo) * CI + d] = acc[oo];
    // cvec: 8 lanes per oo, 16 elements each, reduce within aligned 8-lane groups
    const int oo = d >> 3, j0 = (d & 7) * 16;
    float cv = 0.f;
#pragma unroll
    for (int j = 0; j < 16; ++j) cv += sWo[oo][j0 + j] * sq[j0 + j];
    cv += __shfl_down(cv, 4, 8);
    cv += __shfl_down(cv, 2, 8);
    cv += __shfl_down(cv, 1, 8);
    if ((d & 7) == 0) cvec[n * C + o0 + oo] = cv + b_out[o0 + oo];
}

// ---------------------------------------------------------------------------
// K4: M_n[o,c2] = sum_d W_n[o,d] * w_g[d,c2]  (fp32 + bf16 copies)
// 16 o-rows per block so w_g streams once per block.
__global__ __launch_bounds__(256) void k_M(const float* __restrict__ W,
        const float* __restrict__ w_g, float* __restrict__ M,
        unsigned short* __restrict__ Mb16) {
    const int n = blockIdx.x >> 4, o0 = (blockIdx.x & 15) * 16;
    const int tid = threadIdx.x, c2 = tid;
    __shared__ float sWt[CI][20];
    for (int idx = tid; idx < 16 * CI; idx += 256) {
        const int oo = idx >> 7, d = idx & 127;
        sWt[d][oo] = W[((size_t)n * C + o0 + oo) * CI + d];
    }
    __syncthreads();
    float acc[16] = {};
    for (int d = 0; d < CI; ++d) {
        const float g = w_g[d * C + c2];
        const float4 w0 = *(const float4*)&sWt[d][0];
        const float4 w1 = *(const float4*)&sWt[d][4];
        const float4 w2 = *(const float4*)&sWt[d][8];
        const float4 w3 = *(const float4*)&sWt[d][12];
        acc[0]  += w0.x * g;  acc[1]  += w0.y * g;
        acc[2]  += w0.z * g;  acc[3]  += w0.w * g;
        acc[4]  += w1.x * g;  acc[5]  += w1.y * g;
        acc[6]  += w1.z * g;  acc[7]  += w1.w * g;
        acc[8]  += w2.x * g;  acc[9]  += w2.y * g;
        acc[10] += w2.z * g;  acc[11] += w2.w * g;
        acc[12] += w3.x * g;  acc[13] += w3.y * g;
        acc[14] += w3.z * g;  acc[15] += w3.w * g;
    }
    float* Mp = M + ((size_t)n * C + o0) * C + c2;
#pragma unroll
    for (int oo = 0; oo < 16; ++oo) Mp[(size_t)oo * C] = acc[oo];
    if (Mb16) {
        unsigned short* Mbp = Mb16 + ((size_t)n * C + o0) * C + c2;
#pragma unroll
        for (int oo = 0; oo < 16; ++oo) Mbp[(size_t)oo * C] = f2bf(acc[oo]);
    }
}

// ---------------------------------------------------------------------------
// K5: MFMA GEMM  p[n] = M_n @ x[n] + cvec, fp16 out to ws p16.
// LDS-staged, double-buffered (global_load_lds width=16), BK=32, 128x128 tile.
// Epilogue accumulates per-(n,channel) BN partials (sum p, sum p^2) in fp32.
__global__ __launch_bounds__(256, 4) void k_gemm_mfma(
        const unsigned short* __restrict__ xT,   // [n][4096][256] bf16
        const unsigned short* __restrict__ Mb,   // [n][256][256] bf16
        const float* __restrict__ cvec,
        unsigned short* __restrict__ p16,        // [n][256][4096] fp16
        float* __restrict__ bsum, float* __restrict__ bsq) {
    const int n  = blockIdx.y;
    const int tt = (blockIdx.x & 31) * 128;
    const int ot = (blockIdx.x >> 5) * 128;
    const int tid = threadIdx.x;
    const int wave = tid >> 6, lane = tid & 63;
    const int wm = (wave >> 1) * 64, wn = (wave & 1) * 64;
    const int l15 = lane & 15, q4 = lane >> 4;   // logical 16B k-slot 0..3

    __shared__ unsigned short lA[2][128 * 32];   // [row 128][k 32], 8 KB/buf
    __shared__ unsigned short lB[2][128 * 32];

    const int srow  = tid >> 2;                      // 0..63 (+64 for 2nd call)
    const int sslot = (tid & 3) ^ (srow & 3);
    const unsigned short* gA = Mb + ((size_t)n * C + ot + srow) * C + sslot * 8;
    const unsigned short* gB = xT + ((size_t)n * HW + tt + srow) * C + sslot * 8;
    const int wbase = (tid & ~63) * 8;               // wave-uniform LDS ushort idx

#define STAGE(bf, k0) do { \
        gl16(gA + (k0),           &lA[bf][wbase]); \
        gl16(gA + (k0) + 64 * C,  &lA[bf][2048 + wbase]); \
        gl16(gB + (k0),           &lB[bf][wbase]); \
        gl16(gB + (k0) + 64 * C,  &lB[bf][2048 + wbase]); \
    } while (0)

    const int aoff = (wm + l15) * 32 + ((q4 ^ (l15 & 3)) * 8);
    const int boff = (wn + l15) * 32 + ((q4 ^ (l15 & 3)) * 8);

    floatx4 acc[4][4] = {};
    STAGE(0, 0);
    for (int kt = 0; kt < 8; ++kt) {
        __syncthreads();                 // drains vmcnt: buf[kt&1] staged & safe
        const int b = kt & 1;
        if (kt < 7) STAGE(b ^ 1, (kt + 1) * 32);   // async prefetch next tile
        short8 a[4], bb[4];
#pragma unroll
        for (int i = 0; i < 4; ++i) a[i]  = *(const short8*)&lA[b][aoff + i * 512];
#pragma unroll
        for (int j = 0; j < 4; ++j) bb[j] = *(const short8*)&lB[b][boff + j * 512];
#pragma unroll
        for (int i = 0; i < 4; ++i)
#pragma unroll
            for (int j = 0; j < 4; ++j)
                acc[i][j] = __builtin_amdgcn_mfma_f32_16x16x32_bf16(
                    a[i], bb[j], acc[i][j], 0, 0, 0);
    }
#undef STAGE

    const int quad = lane >> 4;
#pragma unroll
    for (int i = 0; i < 4; ++i) {
        const int rowb = ot + wm + i * 16 + quad * 4;
#pragma unroll
        for (int r = 0; r < 4; ++r) {
            const int row = rowb + r;
            const float cv = cvec[n * C + row];
            unsigned short* orow = p16 + ((size_t)n * C + row) * HW + tt + wn + l15;
            const float v0 = acc[i][0][r] + cv;
            const float v1 = acc[i][1][r] + cv;
            const float v2 = acc[i][2][r] + cv;
            const float v3 = acc[i][3][r] + cv;
            orow[0]  = f2h(v0);
            orow[16] = f2h(v1);
            orow[32] = f2h(v2);
            orow[48] = f2h(v3);
            float s0 = v0 + v1 + v2 + v3;
            float s1 = v0 * v0 + v1 * v1 + v2 * v2 + v3 * v3;
#pragma unroll
            for (int off = 1; off < 16; off <<= 1) {
                s0 += __shfl_xor(s0, off, 64);
                s1 += __shfl_xor(s1, off, 64);
            }
            if (l15 == 0) {
                atomicAdd(&bsum[n * C + row], s0);
                atomicAdd(&bsq [n * C + row], s1);
            }
        }
    }
}

// ---------------------------------------------------------------------------
// K5-fallback: fp32 SGEMM (no atomics) if ws too small for xT.
#define BM 64
#define BN 64
#define BK 16
__global__ __launch_bounds__(256) void k_gemm_f32(const float* __restrict__ x,
        const float* __restrict__ M, const float* __restrict__ cvec,
        float* __restrict__ pout) {
    const int n  = blockIdx.y;
    const int ot = (blockIdx.x >> 6) * BM;
    const int tt = (blockIdx.x & 63) * BN;
    const float* Mb = M + (size_t)n * C * C;
    const float* xb = x + (size_t)n * C * HW;
    __shared__ float sA[BK][BM];
    __shared__ float sB[BK][BN];
    const int tid = threadIdx.x;
    const int ty = tid >> 4, tx = tid & 15;
    float acc[4][4] = {};
    for (int k0 = 0; k0 < C; k0 += BK) {
        {
            int row = tid >> 2, kq = (tid & 3) << 2;
            const float4 v = *(const float4*)&Mb[(size_t)(ot + row) * C + k0 + kq];
            sA[kq + 0][row] = v.x; sA[kq + 1][row] = v.y;
            sA[kq + 2][row] = v.z; sA[kq + 3][row] = v.w;
        }
        {
            int krow = tid >> 4, tq2 = (tid & 15) << 2;
            const float4 v = *(const float4*)&xb[(size_t)(k0 + krow) * HW + tt + tq2];
            *(float4*)&sB[krow][tq2] = v;
        }
        __syncthreads();
#pragma unroll
        for (int kk = 0; kk < BK; ++kk) {
            float a[4], b[4];
#pragma unroll
            for (int i = 0; i < 4; ++i) a[i] = sA[kk][ty * 4 + i];
#pragma unroll
            for (int j = 0; j < 4; ++j) b[j] = sB[kk][tx * 4 + j];
#pragma unroll
            for (int i = 0; i < 4; ++i)
#pragma unroll
                for (int j = 0; j < 4; ++j) acc[i][j] += a[i] * b[j];
        }
        __syncthreads();
    }
#pragma unroll
    for (int i = 0; i < 4; ++i) {
        const int o = ot + ty * 4 + i;
        const float cv = cvec[n * C + o];
        float4 v;
        v.x = acc[i][0] + cv; v.y = acc[i][1] + cv;
        v.z = acc[i][2] + cv; v.w = acc[i][3] + cv;
        *(float4*)&pout[((size_t)n * C + o) * HW + tt + tx * 4] = v;
    }
}

// ---------------------------------------------------------------------------
// K6 (fallback path only): per-channel BN stats -> scale/shift.
__global__ __launch_bounds__(256) void k_bnstat(const float* __restrict__ p,
        const float* __restrict__ gamma, const float* __restrict__ beta,
        float* __restrict__ scale, float* __restrict__ shift) {
    const int o = blockIdx.x;
    float s0 = 0.f, s1 = 0.f;
    for (int n = 0; n < NB; ++n) {
        const float4* pp = (const float4*)(p + ((size_t)n * C + o) * HW);
        for (int i = threadIdx.x; i < HW / 4; i += 256) {
            const float4 v = pp[i];
            s0 += v.x + v.y + v.z + v.w;
            s1 += v.x * v.x + v.y * v.y + v.z * v.z + v.w * v.w;
        }
    }
    for (int off = 32; off; off >>= 1) {
        s0 += __shfl_down(s0, off, 64);
        s1 += __shfl_down(s1, off, 64);
    }
    __shared__ float r0[4], r1[4];
    if ((threadIdx.x & 63) == 0) { r0[threadIdx.x >> 6] = s0; r1[threadIdx.x >> 6] = s1; }
    __syncthreads();
    if (threadIdx.x == 0) {
        const float S0 = r0[0] + r0[1] + r0[2] + r0[3];
        const float S1 = r1[0] + r1[1] + r1[2] + r1[3];
        const float mean = S0 * (1.f / (float)NHW);
        const float var  = S1 * (1.f / (float)NHW) - mean * mean;
        const float sc   = gamma[o] * rsqrtf(var + 1e-5f);
        scale[o] = sc;
        shift[o] = beta[o] - mean * sc;
    }
}

// ---------------------------------------------------------------------------
// K6': reduce per-(n,o) GEMM partials -> scale/shift. 1 block, 256 threads.
__global__ __launch_bounds__(256) void k_scale(const float* __restrict__ bsum,
        const float* __restrict__ bsq,
        const float* __restrict__ gamma, const float* __restrict__ beta,
        float* __restrict__ scale, float* __restrict__ shift) {
    const int o = threadIdx.x;
    float S0 = 0.f, S1 = 0.f;
    for (int n = 0; n < NB; ++n) {
        S0 += bsum[n * C + o];
        S1 += bsq [n * C + o];
    }
    const float mean = S0 * (1.f / (float)NHW);
    const float var  = S1 * (1.f / (float)NHW) - mean * mean;
    const float sc   = gamma[o] * rsqrtf(var + 1e-5f);
    scale[o] = sc;
    shift[o] = beta[o] - mean * sc;
}

// ---------------------------------------------------------------------------
// K7: out = x + scale[c]*p16 + shift[c]   (p16 fp16 in ws, out written fresh)
__global__ __launch_bounds__(256) void k_final16(const float* __restrict__ x,
        const unsigned short* __restrict__ p16, float* __restrict__ out,
        const float* __restrict__ scale, const float* __restrict__ shift) {
    const size_t total8 = (size_t)NB * C * HW / 8;
    size_t i = (size_t)blockIdx.x * 256 + threadIdx.x;
    const size_t stride = (size_t)gridDim.x * 256;
    for (; i < total8; i += stride) {
        const int c = (int)((i >> 9) & 255);
        const float sc = scale[c], sh = shift[c];
        const short8 pv = ((const short8*)p16)[i];
        const float4 x0 = ((const float4*)x)[2 * i];
        const float4 x1 = ((const float4*)x)[2 * i + 1];
        float4 r0, r1;
        r0.x = x0.x + sc * h2f((unsigned short)pv[0]) + sh;
        r0.y = x0.y + sc * h2f((unsigned short)pv[1]) + sh;
        r0.z = x0.z + sc * h2f((unsigned short)pv[2]) + sh;
        r0.w = x0.w + sc * h2f((unsigned short)pv[3]) + sh;
        r1.x = x1.x + sc * h2f((unsigned short)pv[4]) + sh;
        r1.y = x1.y + sc * h2f((unsigned short)pv[5]) + sh;
        r1.z = x1.z + sc * h2f((unsigned short)pv[6]) + sh;
        r1.w = x1.w + sc * h2f((unsigned short)pv[7]) + sh;
        ((float4*)out)[2 * i]     = r0;
        ((float4*)out)[2 * i + 1] = r1;
    }
}

// K7-fallback: out = x + scale[c]*p + shift[c]  (in-place on d_out holding fp32 p)
__global__ __launch_bounds__(256) void k_final32(const float* __restrict__ x,
        float* __restrict__ out, const float* __restrict__ scale,
        const float* __restrict__ shift) {
    const size_t total4 = (size_t)NB * C * HW / 4;
    size_t i = (size_t)blockIdx.x * 256 + threadIdx.x;
    const size_t stride = (size_t)gridDim.x * 256;
    for (; i < total4; i += stride) {
        const int c = (int)((i >> 10) & 255);
        const float sc = scale[c], sh = shift[c];
        const float4 xv = ((const float4*)x)[i];
        const float4 pv = ((float4*)out)[i];
        float4 r;
        r.x = xv.x + sc * pv.x + sh;
        r.y = xv.y + sc * pv.y + sh;
        r.z = xv.z + sc * pv.z + sh;
        r.w = xv.w + sc * pv.w + sh;
        ((float4*)out)[i] = r;
    }
}

// fallback channel-sum kernel (only used when ws is too small for xT)
__global__ __launch_bounds__(256) void k_colsum(const float* __restrict__ x,
                                                float* __restrict__ s) {
    const int bc = blockIdx.x;
    const float4* p4 = (const float4*)(x + (size_t)bc * HW);
    const int tid = threadIdx.x;
    float acc = 0.f;
    for (int i = tid; i < HW / 4; i += 256) {
        const float4 v = p4[i];
        acc += v.x + v.y + v.z + v.w;
    }
    for (int off = 32; off; off >>= 1) acc += __shfl_down(acc, off, 64);
    __shared__ float red[4];
    if ((tid & 63) == 0) red[tid >> 6] = acc;
    __syncthreads();
    if (tid == 0) atomicAdd(&s[bc], red[0] + red[1] + red[2] + red[3]);
}

// ---------------------------------------------------------------------------
extern "C" void kernel_launch(void* const* d_in, const int* in_sizes, int n_in,
                              void* d_out, int out_size, void* d_ws, size_t ws_size,
                              hipStream_t stream) {
    const float* x       = (const float*)d_in[0];
    const float* w_theta = (const float*)d_in[1];
    const float* b_theta = (const float*)d_in[2];
    const float* w_phi   = (const float*)d_in[3];
    const float* b_phi   = (const float*)d_in[4];
    const float* w_g     = (const float*)d_in[5];
    const float* b_g     = (const float*)d_in[6];
    const float* w_out   = (const float*)d_in[7];
    const float* b_out   = (const float*)d_in[8];
    const float* gamma   = (const float*)d_in[9];
    const float* beta    = (const float*)d_in[10];
    float* out = (float*)d_out;
    float* ws  = (float*)d_ws;

    // workspace layout (float offsets)
    float* s     = ws;                       // 8192
    float* bsum  = s + NB * C;               // 8192  (BN Σp partials per n,o)
    float* bsq   = bsum + NB * C;            // 8192  (BN Σp² partials per n,o)
    float* th    = bsq + NB * C;             // 4096
    float* ph    = th + NB * CI;             // 4096
    float* pm    = ph + NB * CI;             // 64 (unused, kept for layout)
    float* A     = pm + NB * 2;              // 524288
    float* q     = A + (size_t)NB * CI * CI; // 4096
    float* W     = q + NB * CI;              // 1048576
    float* M     = W + (size_t)NB * C * CI;  // 2097152
    float* cvec  = M + (size_t)NB * C * C;   // 8192
    float* scale = cvec + NB * C;            // 256
    float* shift = scale + C;                // 256
    unsigned short* Mb16 = (unsigned short*)(shift + C);          // 2097152 u16
    unsigned short* xT   = Mb16 + (size_t)NB * C * C;             // 33554432 u16
    unsigned short* p16  = xT + (size_t)NB * HW * C;              // 33554432 u16
    const size_t need_bytes =
        ((char*)(p16 + (size_t)NB * C * HW) - (char*)ws);
    const bool use_mfma = (ws_size >= need_bytes);

    hipMemsetAsync(s, 0, 3 * NB * C * sizeof(float), stream);  // s + bsum + bsq
    if (use_mfma) {
        k_prep<<<dim3(64, 4, NB), 256, 0, stream>>>(x, xT, s);
    } else {
        k_colsum<<<NB * C, 256, 0, stream>>>(x, s);
    }
    k_thph<<<NB * 8, 256, 0, stream>>>(s, w_theta, b_theta, w_phi, b_phi, th, ph);
    k_arow<<<NB * CI, 64, 0, stream>>>(th, ph, b_g, A, q);
    k_W<<<NB * 16, 128, 0, stream>>>(w_out, A, q, b_out, W, cvec);
    k_M<<<NB * 16, 256, 0, stream>>>(W, w_g, M, use_mfma ? Mb16 : (unsigned short*)nullptr);
    if (use_mfma) {
        k_gemm_mfma<<<dim3(64, NB), 256, 0, stream>>>(xT, Mb16, cvec, p16, bsum, bsq);
        k_scale<<<1, 256, 0, stream>>>(bsum, bsq, gamma, beta, scale, shift);
        k_final16<<<16384, 256, 0, stream>>>(x, p16, out, scale, shift);
    } else {
        k_gemm_f32<<<dim3(256, NB), 256, 0, stream>>>(x, M, cvec, out);
        k_bnstat<<<C, 256, 0, stream>>>(out, gamma, beta, scale, shift);
        k_final32<<<32768, 256, 0, stream>>>(x, out, scale, shift);
    }
}